// Round 13
// baseline (2317.729 us; speedup 1.0000x reference)
//
#include <hip/hip_runtime.h>

// ---------------------------------------------------------------------------
// GRANGER — R13.
// nets: 2 blocks/CU. grid (p=64, btile=8 of 8 rows) = 512 blocks, 512 thr,
// __launch_bounds__(512,4) (VGPR cap 128 — measured exactly 128 in R12).
// MFMA m-tile padded: rows 8-15 carry bounded self-contained garbage (GRU
// rows independent; convex update; never read for output). Reverted R12's
// regressions: late x-gather + f2bf_fast state rounding (RNE gained nothing,
// absmax floor is bf16-h quantization).
// Encoder/cvt unchanged (R12) — total minus nets isolates overhead theory.
// Output layout (fp32): pred[P,B,L,1] | log_var[B,H] | mu[B,H] | mean_[B,P]
// | disp_[B,P]
// ---------------------------------------------------------------------------

#define OFF_LV   409600
#define OFF_MU   425984
#define OFF_MEAN 442368
#define OFF_DISP 446464

// d_ws bf16 bank offsets (elements)
#define OFS_WHHN  0
#define OFS_WHHL  12582912
#define OFS_WIHL  12779520
#define OFS_WIH1  12828672
#define OFS_WMU   13025280
#define OFS_WSTD  13090816
#define OFS_WMEAN 13156352
#define OFS_WDISP 13172736
#define WS_TOTAL  13189120   // elems; *2 bytes = 26,378,240

typedef __attribute__((ext_vector_type(8))) short  bf16x8;
typedef __attribute__((ext_vector_type(4))) float  f32x4;

__device__ __forceinline__ float bf2f(unsigned short u) {
    union { unsigned int i; float f; } v; v.i = ((unsigned int)u) << 16; return v.f;
}
__device__ __forceinline__ unsigned short f2bf(float f) {
    union { float f; unsigned int i; } v; v.f = f;
    unsigned int x = v.i;
    return (unsigned short)((x + 0x7FFFu + ((x >> 16) & 1u)) >> 16);
}
__device__ __forceinline__ unsigned short f2bf_fast(float f) {
    return (unsigned short)((__float_as_uint(f) + 0x8000u) >> 16);
}
__device__ __forceinline__ bf16x8 pack8(const float* pf) {
    union { unsigned int u[4]; bf16x8 v; } r;
    const float4 a = *(const float4*)pf;
    const float4 b = *(const float4*)(pf + 4);
    r.u[0] = ((__float_as_uint(a.x) + 0x8000u) >> 16) | ((__float_as_uint(a.y) + 0x8000u) & 0xFFFF0000u);
    r.u[1] = ((__float_as_uint(a.z) + 0x8000u) >> 16) | ((__float_as_uint(a.w) + 0x8000u) & 0xFFFF0000u);
    r.u[2] = ((__float_as_uint(b.x) + 0x8000u) >> 16) | ((__float_as_uint(b.y) + 0x8000u) & 0xFFFF0000u);
    r.u[3] = ((__float_as_uint(b.z) + 0x8000u) >> 16) | ((__float_as_uint(b.w) + 0x8000u) & 0xFFFF0000u);
    return r.v;
}
// rcpf-based, inf-safe
__device__ __forceinline__ float sigm(float x) {
    return __builtin_amdgcn_rcpf(1.0f + __expf(-x));
}
__device__ __forceinline__ float tanh_fast(float x) {
    return 2.0f * __builtin_amdgcn_rcpf(1.0f + __expf(-2.0f * x)) - 1.0f;
}

#define MFMA(a, b, c) __builtin_amdgcn_mfma_f32_16x16x32_bf16((a), (b), (c), 0, 0, 0)

// ---------------------------------------------------------------------------
// cvt_all: all fp32 weight tensors -> bf16 bank in d_ws.
// ---------------------------------------------------------------------------
#define CVT_N1 3145728   // 12582912/4
#define CVT_N2 151552
__global__ __launch_bounds__(256) void cvt_all_kernel(
    const float* __restrict__ Whhn,
    const float* __restrict__ Whhl, const float* __restrict__ Wihl,
    const float* __restrict__ Wih1, const float* __restrict__ Wmu,
    const float* __restrict__ Wstd, const float* __restrict__ Wmean,
    const float* __restrict__ Wdisp, unsigned short* __restrict__ ws)
{
    int i4 = blockIdx.x * 256 + threadIdx.x;
    const float* src;
    int idx, dst4;
    if (i4 < CVT_N1) {
        src = Whhn; idx = i4; dst4 = i4;
    } else {
        int k = i4 - CVT_N1;
        if (k >= CVT_N2) return;
        int base;
        if      (k <  49152) { src = Whhl;  base = 0; }
        else if (k <  61440) { src = Wihl;  base = 49152; }
        else if (k < 110592) { src = Wih1;  base = 61440; }
        else if (k < 126976) { src = Wmu;   base = 110592; }
        else if (k < 143360) { src = Wstd;  base = 126976; }
        else if (k < 147456) { src = Wmean; base = 143360; }
        else                 { src = Wdisp; base = 147456; }
        idx = k - base; dst4 = OFS_WHHL / 4 + k;
    }
    float4 a = ((const float4*)src)[idx];
    ushort4 r;
    r.x = f2bf_fast(a.x); r.y = f2bf_fast(a.y);
    r.z = f2bf_fast(a.z); r.w = f2bf_fast(a.w);
    ((ushort4*)ws)[dst4] = r;
}

// ---------------------------------------------------------------------------
// Encoder: 4 blocks (16 batch rows each) x 512 thr = 8 waves (R12, unchanged).
// ---------------------------------------------------------------------------
template <bool WS>
__global__ __launch_bounds__(512, 2) void encoder_mfma(
    const float* __restrict__ X,
    const float* __restrict__ Wihl_f, const float* __restrict__ Whhl_f,
    const float* __restrict__ bihl,   const float* __restrict__ bhhl,
    const float* __restrict__ Wih1_f, const float* __restrict__ bih1,
    const float* __restrict__ bhh1,
    const float* __restrict__ Wmu_f,  const float* __restrict__ bmu,
    const float* __restrict__ Wstd_f, const float* __restrict__ bstd,
    const float* __restrict__ Wmean_f,const float* __restrict__ bmean,
    const float* __restrict__ Wdisp_f,const float* __restrict__ bdisp,
    const unsigned short* __restrict__ ws,
    float* __restrict__ out)
{
    const int b0   = blockIdx.x * 16;
    const int tid  = threadIdx.x;
    const int wave = tid >> 6;
    const int lane = tid & 63;
    const int quad = lane >> 4;
    const int ncol = lane & 15;
    const int j0   = wave * 32 + ncol;
    const int j1   = j0 + 16;

    __shared__ __align__(16) unsigned short hs[2][16][264];
    __shared__ __align__(16) unsigned short xs[2][16][72];
    __shared__ float bR[256], bZ[256], bIN[256], bHN[256];
    __shared__ float b1R[256], b1Z[256], b1IN[256], b1HN[256];

    for (int i = tid; i < 256; i += 512) {
        bR[i]   = bihl[i]       + bhhl[i];
        bZ[i]   = bihl[256 + i] + bhhl[256 + i];
        bIN[i]  = bihl[512 + i];
        bHN[i]  = bhhl[512 + i];
        b1R[i]  = bih1[i]       + bhh1[i];
        b1Z[i]  = bih1[256 + i] + bhh1[256 + i];
        b1IN[i] = bih1[512 + i];
        b1HN[i] = bhh1[512 + i];
    }
    for (int i = tid; i < 16 * 264; i += 512)
        (&hs[0][0][0])[i] = 0;                       // h0 = 0
    for (int i = tid; i < 1024; i += 512) {
        int b = i >> 6, f = i & 63;
        xs[0][b][f] = f2bf_fast(X[((b0 + b) * 110 + 0) * 64 + f]);
    }

    float hreg[2][4];
    #pragma unroll
    for (int s = 0; s < 2; s++)
        #pragma unroll
        for (int r = 0; r < 4; r++) hreg[s][r] = 0.f;

    const unsigned short* wsWIHL = ws + OFS_WIHL;
    const unsigned short* wsWHHL = ws + OFS_WHHL;
    const unsigned short* wsWIH1 = ws + OFS_WIH1;
    const unsigned short* wsWMU  = ws + OFS_WMU;
    const unsigned short* wsWSTD = ws + OFS_WSTD;
    const unsigned short* wsWMEAN= ws + OFS_WMEAN;
    const unsigned short* wsWDISP= ws + OFS_WDISP;

    __syncthreads();

    // ---- gru_left: 10 MFMA steps ----
    for (int t = 0; t < 10; t++) {
        const int cur = t & 1, nxt = cur ^ 1;
        f32x4 acc_r[2]  = {{0,0,0,0},{0,0,0,0}};
        f32x4 acc_z[2]  = {{0,0,0,0},{0,0,0,0}};
        f32x4 acc_in[2] = {{0,0,0,0},{0,0,0,0}};
        f32x4 acc_hn[2] = {{0,0,0,0},{0,0,0,0}};

        #pragma unroll
        for (int ks = 0; ks < 2; ks++) {
            const int ko = ks * 32 + quad * 8;
            bf16x8 a = *(const bf16x8*)&xs[cur][ncol][ks * 32 + quad * 8];
            #pragma unroll
            for (int s = 0; s < 2; s++) {
                const int j = s ? j1 : j0;
                bf16x8 br = WS ? *(const bf16x8*)(wsWIHL + (j)       * 64 + ko) : pack8(Wihl_f + (j)       * 64 + ko);
                bf16x8 bz = WS ? *(const bf16x8*)(wsWIHL + (256 + j) * 64 + ko) : pack8(Wihl_f + (256 + j) * 64 + ko);
                bf16x8 bn = WS ? *(const bf16x8*)(wsWIHL + (512 + j) * 64 + ko) : pack8(Wihl_f + (512 + j) * 64 + ko);
                acc_r[s]  = MFMA(a, br, acc_r[s]);
                acc_z[s]  = MFMA(a, bz, acc_z[s]);
                acc_in[s] = MFMA(a, bn, acc_in[s]);
            }
        }
        #pragma unroll 2
        for (int ks = 0; ks < 8; ks++) {
            const int ko = ks * 32 + quad * 8;
            bf16x8 a = *(const bf16x8*)&hs[cur][ncol][ks * 32 + quad * 8];
            #pragma unroll
            for (int s = 0; s < 2; s++) {
                const int j = s ? j1 : j0;
                bf16x8 br = WS ? *(const bf16x8*)(wsWHHL + (size_t)(j)       * 256 + ko) : pack8(Whhl_f + (size_t)(j)       * 256 + ko);
                bf16x8 bz = WS ? *(const bf16x8*)(wsWHHL + (size_t)(256 + j) * 256 + ko) : pack8(Whhl_f + (size_t)(256 + j) * 256 + ko);
                bf16x8 bn = WS ? *(const bf16x8*)(wsWHHL + (size_t)(512 + j) * 256 + ko) : pack8(Whhl_f + (size_t)(512 + j) * 256 + ko);
                acc_r[s]  = MFMA(a, br, acc_r[s]);
                acc_z[s]  = MFMA(a, bz, acc_z[s]);
                acc_hn[s] = MFMA(a, bn, acc_hn[s]);
            }
        }
        #pragma unroll
        for (int s = 0; s < 2; s++) {
            const int j = s ? j1 : j0;
            #pragma unroll
            for (int r = 0; r < 4; r++) {
                float rg = sigm(acc_r[s][r] + bR[j]);
                float zg = sigm(acc_z[s][r] + bZ[j]);
                float nn = tanh_fast(acc_in[s][r] + bIN[j] + rg * (acc_hn[s][r] + bHN[j]));
                float hv = (1.f - zg) * nn + zg * hreg[s][r];
                hreg[s][r] = hv;
                hs[nxt][quad * 4 + r][j] = f2bf(hv);
            }
        }
        if (t < 9)
            for (int i = tid; i < 1024; i += 512) {
                int b = i >> 6, f = i & 63;
                xs[nxt][b][f] = f2bf_fast(X[((b0 + b) * 110 + (t + 1)) * 64 + f]);
            }
        __syncthreads();
    }

    // ---- gru_1 ----
    {
        f32x4 acc_r[2]  = {{0,0,0,0},{0,0,0,0}};
        f32x4 acc_z[2]  = {{0,0,0,0},{0,0,0,0}};
        f32x4 acc_in[2] = {{0,0,0,0},{0,0,0,0}};
        #pragma unroll 2
        for (int ks = 0; ks < 8; ks++) {
            const int ko = ks * 32 + quad * 8;
            bf16x8 a = *(const bf16x8*)&hs[0][ncol][ks * 32 + quad * 8];
            #pragma unroll
            for (int s = 0; s < 2; s++) {
                const int j = s ? j1 : j0;
                bf16x8 br = WS ? *(const bf16x8*)(wsWIH1 + (size_t)(j)       * 256 + ko) : pack8(Wih1_f + (size_t)(j)       * 256 + ko);
                bf16x8 bz = WS ? *(const bf16x8*)(wsWIH1 + (size_t)(256 + j) * 256 + ko) : pack8(Wih1_f + (size_t)(256 + j) * 256 + ko);
                bf16x8 bn = WS ? *(const bf16x8*)(wsWIH1 + (size_t)(512 + j) * 256 + ko) : pack8(Wih1_f + (size_t)(512 + j) * 256 + ko);
                acc_r[s]  = MFMA(a, br, acc_r[s]);
                acc_z[s]  = MFMA(a, bz, acc_z[s]);
                acc_in[s] = MFMA(a, bn, acc_in[s]);
            }
        }
        #pragma unroll
        for (int s = 0; s < 2; s++) {
            const int j = s ? j1 : j0;
            #pragma unroll
            for (int r = 0; r < 4; r++) {
                float rg = sigm(acc_r[s][r] + b1R[j]);
                float zg = sigm(acc_z[s][r] + b1Z[j]);
                float nn = tanh_fast(acc_in[s][r] + b1IN[j] + rg * b1HN[j]);
                float hv = (1.f - zg) * nn;
                hs[1][quad * 4 + r][j] = f2bf(hv);
            }
        }
        __syncthreads();
    }

    // ---- heads ----
    {
        f32x4 acc_mu[2] = {{0,0,0,0},{0,0,0,0}};
        f32x4 acc_lv[2] = {{0,0,0,0},{0,0,0,0}};
        f32x4 acc_md[2] = {{0,0,0,0},{0,0,0,0}};
        const bool do_mean = (wave < 2), do_disp = (wave >= 2 && wave < 4);
        const int jm0 = (wave & 1) * 32 + ncol, jm1 = jm0 + 16;

        #pragma unroll 2
        for (int ks = 0; ks < 8; ks++) {
            const int ko = ks * 32 + quad * 8;
            bf16x8 a = *(const bf16x8*)&hs[1][ncol][ks * 32 + quad * 8];
            #pragma unroll
            for (int s = 0; s < 2; s++) {
                const int j = s ? j1 : j0;
                bf16x8 bmu8 = WS ? *(const bf16x8*)(wsWMU  + (size_t)j * 256 + ko) : pack8(Wmu_f  + (size_t)j * 256 + ko);
                bf16x8 blv8 = WS ? *(const bf16x8*)(wsWSTD + (size_t)j * 256 + ko) : pack8(Wstd_f + (size_t)j * 256 + ko);
                acc_mu[s] = MFMA(a, bmu8, acc_mu[s]);
                acc_lv[s] = MFMA(a, blv8, acc_lv[s]);
                if (do_mean || do_disp) {
                    const int jm = s ? jm1 : jm0;
                    bf16x8 md8;
                    if (do_mean) md8 = WS ? *(const bf16x8*)(wsWMEAN + (size_t)jm * 256 + ko) : pack8(Wmean_f + (size_t)jm * 256 + ko);
                    else         md8 = WS ? *(const bf16x8*)(wsWDISP + (size_t)jm * 256 + ko) : pack8(Wdisp_f + (size_t)jm * 256 + ko);
                    acc_md[s] = MFMA(a, md8, acc_md[s]);
                }
            }
        }
        #pragma unroll
        for (int s = 0; s < 2; s++) {
            const int j = s ? j1 : j0;
            const float bmu_v = bmu[j], blv_v = bstd[j];
            #pragma unroll
            for (int r = 0; r < 4; r++) {
                int b = b0 + quad * 4 + r;
                out[OFF_MU + b * 256 + j] = acc_mu[s][r] + bmu_v;
                out[OFF_LV + b * 256 + j] = acc_lv[s][r] + blv_v;
            }
        }
        if (do_mean) {
            #pragma unroll
            for (int s = 0; s < 2; s++) {
                const int jm = s ? jm1 : jm0;
                const float bm = bmean[jm];
                #pragma unroll
                for (int r = 0; r < 4; r++) {
                    int b = b0 + quad * 4 + r;
                    out[OFF_MEAN + b * 64 + jm] =
                        fminf(fmaxf(__expf(acc_md[s][r] + bm), 1e-5f), 1e6f);
                }
            }
        } else if (do_disp) {
            #pragma unroll
            for (int s = 0; s < 2; s++) {
                const int jm = s ? jm1 : jm0;
                const float bd = bdisp[jm];
                #pragma unroll
                for (int r = 0; r < 4; r++) {
                    int b = b0 + quad * 4 + r;
                    float v = acc_md[s][r] + bd;
                    float sp = (v > 20.f) ? v : log1pf(__expf(v));
                    out[OFF_DISP + b * 64 + jm] = fminf(fmaxf(sp, 1e-4f), 1e4f);
                }
            }
        }
    }
}

// ---------------------------------------------------------------------------
// Nets: grid (p=64, btile=8 of 8 rows) = 512 blocks, 512 thr = 8 waves,
// __launch_bounds__(512,4) -> 2 blocks/CU (16 waves/CU). MFMA m-rows 8-15
// carry bounded self-contained garbage (never read for output; GRU rows
// independent, convex update). Register-resident W_hh, rcpf gates, ping-pong
// LDS, single barrier/step, late x-gather, f2bf_fast state (R11 config).
// ---------------------------------------------------------------------------
template <bool WS>
__global__ __launch_bounds__(512, 4) void nets_kernel(
    const float*          __restrict__ X,
    const int*            __restrict__ conn,
    const float*          __restrict__ Wih,
    const float*          __restrict__ Whh_f,
    const unsigned short* __restrict__ Whh_b,
    const float*          __restrict__ bih,
    const float*          __restrict__ bhh,
    const float*          __restrict__ Wlin,
    const float*          __restrict__ blin,
    const float*          __restrict__ znoise,
    float*                __restrict__ out)
{
    const int p    = blockIdx.x;
    const int b0   = blockIdx.y * 8;          // 8 batch rows per block
    const int tid  = threadIdx.x;
    const int wave = tid >> 6;
    const int lane = tid & 63;
    const int quad = lane >> 4;
    const int ncol = lane & 15;
    const int j0   = wave * 32 + ncol;
    const int j1   = j0 + 16;

    __shared__ __align__(16) unsigned short hs[2][16][264];
    __shared__ __align__(16) unsigned short xs[2][16][16];
    __shared__ __align__(16) unsigned short wih_s[768][16];
    __shared__ float bR[256], bZ[256], bIN[256], bHN[256], wlin_s[256];
    __shared__ float predw[2][8][16];
    __shared__ int   conn_s[16];

    for (int i = tid; i < 768 * 16; i += 512)
        (&wih_s[0][0])[i] = f2bf_fast(Wih[p * 768 * 16 + i]);
    for (int i = tid; i < 256; i += 512) {
        bR[i]  = bih[p * 768 + i]       + bhh[p * 768 + i];
        bZ[i]  = bih[p * 768 + 256 + i] + bhh[p * 768 + 256 + i];
        bIN[i] = bih[p * 768 + 512 + i];
        bHN[i] = bhh[p * 768 + 512 + i];
        wlin_s[i] = Wlin[p * 256 + i];
    }
    if (tid < 16) conn_s[tid] = conn[p * 16 + tid];

    // h0: rows 0-7 = z; rows 8-15 = 0 (stay bounded-garbage, never output)
    for (int i = tid; i < 16 * 264; i += 512) {
        int bb = i / 264, jj = i - bb * 264;
        unsigned short v = 0;
        if (jj < 256 && bb < 8) {
            int gi = (b0 + bb) * 256 + jj;
            v = f2bf(out[OFF_MU + gi] + __expf(0.5f * out[OFF_LV + gi]) * znoise[gi]);
        }
        hs[0][bb][jj] = v;
    }
    // xs: both buffers fully zero (rows 8-15 never written again)
    (&xs[0][0][0])[tid] = 0;   // 512 = 2*16*16

    float hreg[2][4];
    #pragma unroll
    for (int s = 0; s < 2; s++)
        #pragma unroll
        for (int r = 0; r < 4; r++) {
            float hv = 0.f;
            if (quad < 2) {   // valid rows 0-7 only (avoid OOB reads)
                int gi = (b0 + quad * 4 + r) * 256 + (s ? j1 : j0);
                hv = out[OFF_MU + gi] + __expf(0.5f * out[OFF_LV + gi]) * znoise[gi];
            }
            hreg[s][r] = hv;
        }

    // preload W_hh fragments (loop-invariant)
    const size_t whh_off = (size_t)p * 768 * 256;
    bf16x8 w_r[2][8], w_z[2][8], w_n[2][8];
    #pragma unroll
    for (int s = 0; s < 2; s++) {
        const int j = s ? j1 : j0;
        #pragma unroll
        for (int k0 = 0; k0 < 8; k0++) {
            const size_t o_r = whh_off + (size_t)(j)       * 256 + k0 * 32 + quad * 8;
            const size_t o_z = whh_off + (size_t)(256 + j) * 256 + k0 * 32 + quad * 8;
            const size_t o_n = whh_off + (size_t)(512 + j) * 256 + k0 * 32 + quad * 8;
            if (WS) {
                w_r[s][k0] = *(const bf16x8*)(Whh_b + o_r);
                w_z[s][k0] = *(const bf16x8*)(Whh_b + o_z);
                w_n[s][k0] = *(const bf16x8*)(Whh_b + o_n);
            } else {
                w_r[s][k0] = pack8(Whh_f + o_r);
                w_z[s][k0] = pack8(Whh_f + o_z);
                w_n[s][k0] = pack8(Whh_f + o_n);
            }
        }
    }

    __syncthreads();

    const float blin_v = blin[p];
    const bf16x8 ZERO8 = {0, 0, 0, 0, 0, 0, 0, 0};

    for (int t = 0; t < 100; t++) {
        const int cur = t & 1, nxt = cur ^ 1;
        f32x4 acc_r[2]  = {{0,0,0,0},{0,0,0,0}};
        f32x4 acc_z[2]  = {{0,0,0,0},{0,0,0,0}};
        f32x4 acc_in[2] = {{0,0,0,0},{0,0,0,0}};
        f32x4 acc_hn[2] = {{0,0,0,0},{0,0,0,0}};

        // x part (K=16 zero-padded)
        {
            bf16x8 a, br0, bz0, bn0, br1, bz1, bn1;
            if (quad < 2) {
                a   = *(const bf16x8*)&xs[cur][ncol][quad * 8];
                br0 = *(const bf16x8*)&wih_s[j0][quad * 8];
                bz0 = *(const bf16x8*)&wih_s[256 + j0][quad * 8];
                bn0 = *(const bf16x8*)&wih_s[512 + j0][quad * 8];
                br1 = *(const bf16x8*)&wih_s[j1][quad * 8];
                bz1 = *(const bf16x8*)&wih_s[256 + j1][quad * 8];
                bn1 = *(const bf16x8*)&wih_s[512 + j1][quad * 8];
            } else {
                a = ZERO8; br0 = bz0 = bn0 = br1 = bz1 = bn1 = ZERO8;
            }
            acc_r[0]  = MFMA(a, br0, acc_r[0]);  acc_r[1]  = MFMA(a, br1, acc_r[1]);
            acc_z[0]  = MFMA(a, bz0, acc_z[0]);  acc_z[1]  = MFMA(a, bz1, acc_z[1]);
            acc_in[0] = MFMA(a, bn0, acc_in[0]); acc_in[1] = MFMA(a, bn1, acc_in[1]);
        }
        // h part: weights from registers
        #pragma unroll
        for (int k0 = 0; k0 < 8; k0++) {
            bf16x8 a = *(const bf16x8*)&hs[cur][ncol][k0 * 32 + quad * 8];
            acc_r[0]  = MFMA(a, w_r[0][k0], acc_r[0]);
            acc_r[1]  = MFMA(a, w_r[1][k0], acc_r[1]);
            acc_z[0]  = MFMA(a, w_z[0][k0], acc_z[0]);
            acc_z[1]  = MFMA(a, w_z[1][k0], acc_z[1]);
            acc_hn[0] = MFMA(a, w_n[0][k0], acc_hn[0]);
            acc_hn[1] = MFMA(a, w_n[1][k0], acc_hn[1]);
        }

        // gates + state update (rows 8-15 produce bounded garbage, contained)
        float pv[4] = {0.f, 0.f, 0.f, 0.f};
        #pragma unroll
        for (int s = 0; s < 2; s++) {
            const int j = s ? j1 : j0;
            const float b_r = bR[j], b_z = bZ[j], b_in = bIN[j], b_hn = bHN[j];
            const float wl = wlin_s[j];
            #pragma unroll
            for (int r = 0; r < 4; r++) {
                float rg = sigm(acc_r[s][r] + b_r);
                float zg = sigm(acc_z[s][r] + b_z);
                float nn = tanh_fast(acc_in[s][r] + b_in + rg * (acc_hn[s][r] + b_hn));
                float hv = (1.f - zg) * nn + zg * hreg[s][r];
                hreg[s][r] = hv;
                pv[r] += fmaxf(hv, 0.f) * wl;
            }
        }
        // reduce across 16 ncol lanes
        #pragma unroll
        for (int r = 0; r < 4; r++) {
            float v = pv[r];
            v += __shfl_xor(v, 1, 64);
            v += __shfl_xor(v, 2, 64);
            v += __shfl_xor(v, 4, 64);
            v += __shfl_xor(v, 8, 64);
            pv[r] = v;
        }

        // writes into nxt buffers (disjoint from cur)
        #pragma unroll
        for (int r = 0; r < 4; r++) {
            hs[nxt][quad * 4 + r][j0] = f2bf_fast(hreg[0][r]);
            hs[nxt][quad * 4 + r][j1] = f2bf_fast(hreg[1][r]);
        }
        if (ncol == 0) {
            #pragma unroll
            for (int r = 0; r < 4; r++)
                predw[cur][wave][quad * 4 + r] = pv[r];
        }
        // late x-gather for t+1 (rows 0-7 only)
        if (tid < 128) {
            int gb = tid >> 4, gk = tid & 15;
            unsigned short v = 0;
            if (t < 99) v = f2bf_fast(X[(size_t)((b0 + gb) * 110 + (10 + t)) * 64 + conn_s[gk]]);
            xs[nxt][gb][gk] = v;
        }

        __syncthreads();   // orders: cur reads & nxt/predw[cur] writes

        if (tid < 8) {
            float s = blin_v;
            #pragma unroll
            for (int w = 0; w < 8; w++) s += predw[cur][w][tid];
            out[(size_t)(p * 64 + b0 + tid) * 100 + t] = s;
        }
    }
}

// ---------------------------------------------------------------------------
extern "C" void kernel_launch(void* const* d_in, const int* in_sizes, int n_in,
                              void* d_out, int out_size, void* d_ws, size_t ws_size,
                              hipStream_t stream) {
    const float* X      = (const float*)d_in[0];
    const int*   conn   = (const int*)d_in[1];
    const float* Wihl   = (const float*)d_in[2];
    const float* Whhl   = (const float*)d_in[3];
    const float* bihl   = (const float*)d_in[4];
    const float* bhhl   = (const float*)d_in[5];
    const float* Wih1   = (const float*)d_in[6];
    // d_in[7] = W_hh_1 unused: gru_1's h0 is 0, so gh reduces to b_hh_1
    const float* bih1   = (const float*)d_in[8];
    const float* bhh1   = (const float*)d_in[9];
    const float* Wmu    = (const float*)d_in[10];
    const float* bmu    = (const float*)d_in[11];
    const float* Wstd   = (const float*)d_in[12];
    const float* bstd   = (const float*)d_in[13];
    const float* Wmean  = (const float*)d_in[14];
    const float* bmean  = (const float*)d_in[15];
    const float* Wdisp  = (const float*)d_in[16];
    const float* bdisp  = (const float*)d_in[17];
    const float* Wihn   = (const float*)d_in[18];
    const float* Whhn   = (const float*)d_in[19];
    const float* bihn   = (const float*)d_in[20];
    const float* bhhn   = (const float*)d_in[21];
    const float* Wlin   = (const float*)d_in[22];
    const float* blin   = (const float*)d_in[23];
    const float* znoise = (const float*)d_in[24];

    float* out = (float*)d_out;
    unsigned short* ws = (unsigned short*)d_ws;

    const bool use_ws = (ws_size >= (size_t)WS_TOTAL * 2);

    if (use_ws) {
        const int total4 = CVT_N1 + CVT_N2;
        cvt_all_kernel<<<(total4 + 255) / 256, 256, 0, stream>>>(
            Whhn, Whhl, Wihl, Wih1, Wmu, Wstd, Wmean, Wdisp, ws);
        encoder_mfma<true><<<4, 512, 0, stream>>>(
            X, Wihl, Whhl, bihl, bhhl, Wih1, bih1, bhh1,
            Wmu, bmu, Wstd, bstd, Wmean, bmean, Wdisp, bdisp, ws, out);
        nets_kernel<true><<<dim3(64, 8), 512, 0, stream>>>(
            X, conn, Wihn, Whhn, ws + OFS_WHHN,
            bihn, bhhn, Wlin, blin, znoise, out);
    } else {
        encoder_mfma<false><<<4, 512, 0, stream>>>(
            X, Wihl, Whhl, bihl, bhhl, Wih1, bih1, bhh1,
            Wmu, bmu, Wstd, bstd, Wmean, bmean, Wdisp, bdisp,
            (const unsigned short*)nullptr, out);
        nets_kernel<false><<<dim3(64, 8), 512, 0, stream>>>(
            X, conn, Wihn, Whhn, (const unsigned short*)nullptr,
            bihn, bhhn, Wlin, blin, znoise, out);
    }
}

// Round 14
// 717.554 us; speedup vs baseline: 3.2300x; 3.2300x over previous
//
#include <hip/hip_runtime.h>

// ---------------------------------------------------------------------------
// GRANGER — R14.
// R13 post-mortem: launch_bounds(512,4) capped VGPR at 128 < the 192 needed
// for weight fragments -> full spill to scratch (FETCH 25MB->7.1GB). R14
// reaches 16 waves/CU the register-frugal way: 1024-thr blocks (16 waves),
// each wave owns ONE 16-col j-slice: w_r/w_z register-resident (64 VGPR),
// n-gate weights streamed from L2 with a 2-deep pipeline (8 VGPR window),
// acc 16 + hreg 4 + temps ~ 115 total <= the 128 cap a 1024-thr block
// imposes. Grid (64,4), 16 real batch rows (R13's padded tile reverted).
// Encoder (4x512) / cvt unchanged.
// Output layout (fp32): pred[P,B,L,1] | log_var[B,H] | mu[B,H] | mean_[B,P]
// | disp_[B,P]
// ---------------------------------------------------------------------------

#define OFF_LV   409600
#define OFF_MU   425984
#define OFF_MEAN 442368
#define OFF_DISP 446464

// d_ws bf16 bank offsets (elements)
#define OFS_WHHN  0
#define OFS_WHHL  12582912
#define OFS_WIHL  12779520
#define OFS_WIH1  12828672
#define OFS_WMU   13025280
#define OFS_WSTD  13090816
#define OFS_WMEAN 13156352
#define OFS_WDISP 13172736
#define WS_TOTAL  13189120   // elems; *2 bytes = 26,378,240

typedef __attribute__((ext_vector_type(8))) short  bf16x8;
typedef __attribute__((ext_vector_type(4))) float  f32x4;

__device__ __forceinline__ float bf2f(unsigned short u) {
    union { unsigned int i; float f; } v; v.i = ((unsigned int)u) << 16; return v.f;
}
__device__ __forceinline__ unsigned short f2bf(float f) {
    union { float f; unsigned int i; } v; v.f = f;
    unsigned int x = v.i;
    return (unsigned short)((x + 0x7FFFu + ((x >> 16) & 1u)) >> 16);
}
__device__ __forceinline__ unsigned short f2bf_fast(float f) {
    return (unsigned short)((__float_as_uint(f) + 0x8000u) >> 16);
}
__device__ __forceinline__ bf16x8 pack8(const float* pf) {
    union { unsigned int u[4]; bf16x8 v; } r;
    const float4 a = *(const float4*)pf;
    const float4 b = *(const float4*)(pf + 4);
    r.u[0] = ((__float_as_uint(a.x) + 0x8000u) >> 16) | ((__float_as_uint(a.y) + 0x8000u) & 0xFFFF0000u);
    r.u[1] = ((__float_as_uint(a.z) + 0x8000u) >> 16) | ((__float_as_uint(a.w) + 0x8000u) & 0xFFFF0000u);
    r.u[2] = ((__float_as_uint(b.x) + 0x8000u) >> 16) | ((__float_as_uint(b.y) + 0x8000u) & 0xFFFF0000u);
    r.u[3] = ((__float_as_uint(b.z) + 0x8000u) >> 16) | ((__float_as_uint(b.w) + 0x8000u) & 0xFFFF0000u);
    return r.v;
}
// rcpf-based, inf-safe
__device__ __forceinline__ float sigm(float x) {
    return __builtin_amdgcn_rcpf(1.0f + __expf(-x));
}
__device__ __forceinline__ float tanh_fast(float x) {
    return 2.0f * __builtin_amdgcn_rcpf(1.0f + __expf(-2.0f * x)) - 1.0f;
}

#define MFMA(a, b, c) __builtin_amdgcn_mfma_f32_16x16x32_bf16((a), (b), (c), 0, 0, 0)

// ---------------------------------------------------------------------------
// cvt_all: all fp32 weight tensors -> bf16 bank in d_ws.
// ---------------------------------------------------------------------------
#define CVT_N1 3145728   // 12582912/4
#define CVT_N2 151552
__global__ __launch_bounds__(256) void cvt_all_kernel(
    const float* __restrict__ Whhn,
    const float* __restrict__ Whhl, const float* __restrict__ Wihl,
    const float* __restrict__ Wih1, const float* __restrict__ Wmu,
    const float* __restrict__ Wstd, const float* __restrict__ Wmean,
    const float* __restrict__ Wdisp, unsigned short* __restrict__ ws)
{
    int i4 = blockIdx.x * 256 + threadIdx.x;
    const float* src;
    int idx, dst4;
    if (i4 < CVT_N1) {
        src = Whhn; idx = i4; dst4 = i4;
    } else {
        int k = i4 - CVT_N1;
        if (k >= CVT_N2) return;
        int base;
        if      (k <  49152) { src = Whhl;  base = 0; }
        else if (k <  61440) { src = Wihl;  base = 49152; }
        else if (k < 110592) { src = Wih1;  base = 61440; }
        else if (k < 126976) { src = Wmu;   base = 110592; }
        else if (k < 143360) { src = Wstd;  base = 126976; }
        else if (k < 147456) { src = Wmean; base = 143360; }
        else                 { src = Wdisp; base = 147456; }
        idx = k - base; dst4 = OFS_WHHL / 4 + k;
    }
    float4 a = ((const float4*)src)[idx];
    ushort4 r;
    r.x = f2bf_fast(a.x); r.y = f2bf_fast(a.y);
    r.z = f2bf_fast(a.z); r.w = f2bf_fast(a.w);
    ((ushort4*)ws)[dst4] = r;
}

// ---------------------------------------------------------------------------
// Encoder: 4 blocks (16 batch rows each) x 512 thr = 8 waves (R12, unchanged).
// ---------------------------------------------------------------------------
template <bool WS>
__global__ __launch_bounds__(512, 2) void encoder_mfma(
    const float* __restrict__ X,
    const float* __restrict__ Wihl_f, const float* __restrict__ Whhl_f,
    const float* __restrict__ bihl,   const float* __restrict__ bhhl,
    const float* __restrict__ Wih1_f, const float* __restrict__ bih1,
    const float* __restrict__ bhh1,
    const float* __restrict__ Wmu_f,  const float* __restrict__ bmu,
    const float* __restrict__ Wstd_f, const float* __restrict__ bstd,
    const float* __restrict__ Wmean_f,const float* __restrict__ bmean,
    const float* __restrict__ Wdisp_f,const float* __restrict__ bdisp,
    const unsigned short* __restrict__ ws,
    float* __restrict__ out)
{
    const int b0   = blockIdx.x * 16;
    const int tid  = threadIdx.x;
    const int wave = tid >> 6;
    const int lane = tid & 63;
    const int quad = lane >> 4;
    const int ncol = lane & 15;
    const int j0   = wave * 32 + ncol;
    const int j1   = j0 + 16;

    __shared__ __align__(16) unsigned short hs[2][16][264];
    __shared__ __align__(16) unsigned short xs[2][16][72];
    __shared__ float bR[256], bZ[256], bIN[256], bHN[256];
    __shared__ float b1R[256], b1Z[256], b1IN[256], b1HN[256];

    for (int i = tid; i < 256; i += 512) {
        bR[i]   = bihl[i]       + bhhl[i];
        bZ[i]   = bihl[256 + i] + bhhl[256 + i];
        bIN[i]  = bihl[512 + i];
        bHN[i]  = bhhl[512 + i];
        b1R[i]  = bih1[i]       + bhh1[i];
        b1Z[i]  = bih1[256 + i] + bhh1[256 + i];
        b1IN[i] = bih1[512 + i];
        b1HN[i] = bhh1[512 + i];
    }
    for (int i = tid; i < 16 * 264; i += 512)
        (&hs[0][0][0])[i] = 0;                       // h0 = 0
    for (int i = tid; i < 1024; i += 512) {
        int b = i >> 6, f = i & 63;
        xs[0][b][f] = f2bf_fast(X[((b0 + b) * 110 + 0) * 64 + f]);
    }

    float hreg[2][4];
    #pragma unroll
    for (int s = 0; s < 2; s++)
        #pragma unroll
        for (int r = 0; r < 4; r++) hreg[s][r] = 0.f;

    const unsigned short* wsWIHL = ws + OFS_WIHL;
    const unsigned short* wsWHHL = ws + OFS_WHHL;
    const unsigned short* wsWIH1 = ws + OFS_WIH1;
    const unsigned short* wsWMU  = ws + OFS_WMU;
    const unsigned short* wsWSTD = ws + OFS_WSTD;
    const unsigned short* wsWMEAN= ws + OFS_WMEAN;
    const unsigned short* wsWDISP= ws + OFS_WDISP;

    __syncthreads();

    // ---- gru_left: 10 MFMA steps ----
    for (int t = 0; t < 10; t++) {
        const int cur = t & 1, nxt = cur ^ 1;
        f32x4 acc_r[2]  = {{0,0,0,0},{0,0,0,0}};
        f32x4 acc_z[2]  = {{0,0,0,0},{0,0,0,0}};
        f32x4 acc_in[2] = {{0,0,0,0},{0,0,0,0}};
        f32x4 acc_hn[2] = {{0,0,0,0},{0,0,0,0}};

        #pragma unroll
        for (int ks = 0; ks < 2; ks++) {
            const int ko = ks * 32 + quad * 8;
            bf16x8 a = *(const bf16x8*)&xs[cur][ncol][ks * 32 + quad * 8];
            #pragma unroll
            for (int s = 0; s < 2; s++) {
                const int j = s ? j1 : j0;
                bf16x8 br = WS ? *(const bf16x8*)(wsWIHL + (j)       * 64 + ko) : pack8(Wihl_f + (j)       * 64 + ko);
                bf16x8 bz = WS ? *(const bf16x8*)(wsWIHL + (256 + j) * 64 + ko) : pack8(Wihl_f + (256 + j) * 64 + ko);
                bf16x8 bn = WS ? *(const bf16x8*)(wsWIHL + (512 + j) * 64 + ko) : pack8(Wihl_f + (512 + j) * 64 + ko);
                acc_r[s]  = MFMA(a, br, acc_r[s]);
                acc_z[s]  = MFMA(a, bz, acc_z[s]);
                acc_in[s] = MFMA(a, bn, acc_in[s]);
            }
        }
        #pragma unroll 2
        for (int ks = 0; ks < 8; ks++) {
            const int ko = ks * 32 + quad * 8;
            bf16x8 a = *(const bf16x8*)&hs[cur][ncol][ks * 32 + quad * 8];
            #pragma unroll
            for (int s = 0; s < 2; s++) {
                const int j = s ? j1 : j0;
                bf16x8 br = WS ? *(const bf16x8*)(wsWHHL + (size_t)(j)       * 256 + ko) : pack8(Whhl_f + (size_t)(j)       * 256 + ko);
                bf16x8 bz = WS ? *(const bf16x8*)(wsWHHL + (size_t)(256 + j) * 256 + ko) : pack8(Whhl_f + (size_t)(256 + j) * 256 + ko);
                bf16x8 bn = WS ? *(const bf16x8*)(wsWHHL + (size_t)(512 + j) * 256 + ko) : pack8(Whhl_f + (size_t)(512 + j) * 256 + ko);
                acc_r[s]  = MFMA(a, br, acc_r[s]);
                acc_z[s]  = MFMA(a, bz, acc_z[s]);
                acc_hn[s] = MFMA(a, bn, acc_hn[s]);
            }
        }
        #pragma unroll
        for (int s = 0; s < 2; s++) {
            const int j = s ? j1 : j0;
            #pragma unroll
            for (int r = 0; r < 4; r++) {
                float rg = sigm(acc_r[s][r] + bR[j]);
                float zg = sigm(acc_z[s][r] + bZ[j]);
                float nn = tanh_fast(acc_in[s][r] + bIN[j] + rg * (acc_hn[s][r] + bHN[j]));
                float hv = (1.f - zg) * nn + zg * hreg[s][r];
                hreg[s][r] = hv;
                hs[nxt][quad * 4 + r][j] = f2bf(hv);
            }
        }
        if (t < 9)
            for (int i = tid; i < 1024; i += 512) {
                int b = i >> 6, f = i & 63;
                xs[nxt][b][f] = f2bf_fast(X[((b0 + b) * 110 + (t + 1)) * 64 + f]);
            }
        __syncthreads();
    }

    // ---- gru_1 ----
    {
        f32x4 acc_r[2]  = {{0,0,0,0},{0,0,0,0}};
        f32x4 acc_z[2]  = {{0,0,0,0},{0,0,0,0}};
        f32x4 acc_in[2] = {{0,0,0,0},{0,0,0,0}};
        #pragma unroll 2
        for (int ks = 0; ks < 8; ks++) {
            const int ko = ks * 32 + quad * 8;
            bf16x8 a = *(const bf16x8*)&hs[0][ncol][ks * 32 + quad * 8];
            #pragma unroll
            for (int s = 0; s < 2; s++) {
                const int j = s ? j1 : j0;
                bf16x8 br = WS ? *(const bf16x8*)(wsWIH1 + (size_t)(j)       * 256 + ko) : pack8(Wih1_f + (size_t)(j)       * 256 + ko);
                bf16x8 bz = WS ? *(const bf16x8*)(wsWIH1 + (size_t)(256 + j) * 256 + ko) : pack8(Wih1_f + (size_t)(256 + j) * 256 + ko);
                bf16x8 bn = WS ? *(const bf16x8*)(wsWIH1 + (size_t)(512 + j) * 256 + ko) : pack8(Wih1_f + (size_t)(512 + j) * 256 + ko);
                acc_r[s]  = MFMA(a, br, acc_r[s]);
                acc_z[s]  = MFMA(a, bz, acc_z[s]);
                acc_in[s] = MFMA(a, bn, acc_in[s]);
            }
        }
        #pragma unroll
        for (int s = 0; s < 2; s++) {
            const int j = s ? j1 : j0;
            #pragma unroll
            for (int r = 0; r < 4; r++) {
                float rg = sigm(acc_r[s][r] + b1R[j]);
                float zg = sigm(acc_z[s][r] + b1Z[j]);
                float nn = tanh_fast(acc_in[s][r] + b1IN[j] + rg * b1HN[j]);
                float hv = (1.f - zg) * nn;
                hs[1][quad * 4 + r][j] = f2bf(hv);
            }
        }
        __syncthreads();
    }

    // ---- heads ----
    {
        f32x4 acc_mu[2] = {{0,0,0,0},{0,0,0,0}};
        f32x4 acc_lv[2] = {{0,0,0,0},{0,0,0,0}};
        f32x4 acc_md[2] = {{0,0,0,0},{0,0,0,0}};
        const bool do_mean = (wave < 2), do_disp = (wave >= 2 && wave < 4);
        const int jm0 = (wave & 1) * 32 + ncol, jm1 = jm0 + 16;

        #pragma unroll 2
        for (int ks = 0; ks < 8; ks++) {
            const int ko = ks * 32 + quad * 8;
            bf16x8 a = *(const bf16x8*)&hs[1][ncol][ks * 32 + quad * 8];
            #pragma unroll
            for (int s = 0; s < 2; s++) {
                const int j = s ? j1 : j0;
                bf16x8 bmu8 = WS ? *(const bf16x8*)(wsWMU  + (size_t)j * 256 + ko) : pack8(Wmu_f  + (size_t)j * 256 + ko);
                bf16x8 blv8 = WS ? *(const bf16x8*)(wsWSTD + (size_t)j * 256 + ko) : pack8(Wstd_f + (size_t)j * 256 + ko);
                acc_mu[s] = MFMA(a, bmu8, acc_mu[s]);
                acc_lv[s] = MFMA(a, blv8, acc_lv[s]);
                if (do_mean || do_disp) {
                    const int jm = s ? jm1 : jm0;
                    bf16x8 md8;
                    if (do_mean) md8 = WS ? *(const bf16x8*)(wsWMEAN + (size_t)jm * 256 + ko) : pack8(Wmean_f + (size_t)jm * 256 + ko);
                    else         md8 = WS ? *(const bf16x8*)(wsWDISP + (size_t)jm * 256 + ko) : pack8(Wdisp_f + (size_t)jm * 256 + ko);
                    acc_md[s] = MFMA(a, md8, acc_md[s]);
                }
            }
        }
        #pragma unroll
        for (int s = 0; s < 2; s++) {
            const int j = s ? j1 : j0;
            const float bmu_v = bmu[j], blv_v = bstd[j];
            #pragma unroll
            for (int r = 0; r < 4; r++) {
                int b = b0 + quad * 4 + r;
                out[OFF_MU + b * 256 + j] = acc_mu[s][r] + bmu_v;
                out[OFF_LV + b * 256 + j] = acc_lv[s][r] + blv_v;
            }
        }
        if (do_mean) {
            #pragma unroll
            for (int s = 0; s < 2; s++) {
                const int jm = s ? jm1 : jm0;
                const float bm = bmean[jm];
                #pragma unroll
                for (int r = 0; r < 4; r++) {
                    int b = b0 + quad * 4 + r;
                    out[OFF_MEAN + b * 64 + jm] =
                        fminf(fmaxf(__expf(acc_md[s][r] + bm), 1e-5f), 1e6f);
                }
            }
        } else if (do_disp) {
            #pragma unroll
            for (int s = 0; s < 2; s++) {
                const int jm = s ? jm1 : jm0;
                const float bd = bdisp[jm];
                #pragma unroll
                for (int r = 0; r < 4; r++) {
                    int b = b0 + quad * 4 + r;
                    float v = acc_md[s][r] + bd;
                    float sp = (v > 20.f) ? v : log1pf(__expf(v));
                    out[OFF_DISP + b * 64 + jm] = fminf(fmaxf(sp, 1e-4f), 1e4f);
                }
            }
        }
    }
}

// ---------------------------------------------------------------------------
// Nets: grid (p=64, btile=4 of 16 rows) = 256 blocks, 1024 thr = 16 waves
// -> 16 waves/CU (50% occupancy; 1024-thr block caps VGPR at 128).
// Wave owns ONE 16-col j-slice: w_r/w_z register-resident (64 VGPR),
// n-gate weights streamed from L2 (2-deep pipeline, L2-hot: 4 blocks/p on
// one XCD). acc 16 + hreg 4 + window 8 + temps ~= 115 VGPR total.
// rcpf gates, ping-pong LDS, single barrier/step, late x-gather.
// ---------------------------------------------------------------------------
template <bool WS>
__global__ __launch_bounds__(1024, 1) void nets_kernel(
    const float*          __restrict__ X,
    const int*            __restrict__ conn,
    const float*          __restrict__ Wih,
    const float*          __restrict__ Whh_f,
    const unsigned short* __restrict__ Whh_b,
    const float*          __restrict__ bih,
    const float*          __restrict__ bhh,
    const float*          __restrict__ Wlin,
    const float*          __restrict__ blin,
    const float*          __restrict__ znoise,
    float*                __restrict__ out)
{
    const int p    = blockIdx.x;
    const int b0   = blockIdx.y * 16;
    const int tid  = threadIdx.x;
    const int wave = tid >> 6;       // 0..15
    const int lane = tid & 63;
    const int quad = lane >> 4;
    const int ncol = lane & 15;
    const int j    = wave * 16 + ncol;

    __shared__ __align__(16) unsigned short hs[2][16][264];
    __shared__ __align__(16) unsigned short xs[2][16][16];
    __shared__ __align__(16) unsigned short wih_s[768][16];
    __shared__ float bR[256], bZ[256], bIN[256], bHN[256], wlin_s[256];
    __shared__ float predw[2][16][16];
    __shared__ int   conn_s[16];

    for (int i = tid; i < 768 * 16; i += 1024)
        (&wih_s[0][0])[i] = f2bf_fast(Wih[p * 768 * 16 + i]);
    for (int i = tid; i < 256; i += 1024) {
        bR[i]  = bih[p * 768 + i]       + bhh[p * 768 + i];
        bZ[i]  = bih[p * 768 + 256 + i] + bhh[p * 768 + 256 + i];
        bIN[i] = bih[p * 768 + 512 + i];
        bHN[i] = bhh[p * 768 + 512 + i];
        wlin_s[i] = Wlin[p * 256 + i];
    }
    if (tid < 16) conn_s[tid] = conn[p * 16 + tid];

    for (int i = tid; i < 16 * 264; i += 1024) {
        int bb = i / 264, jj = i - bb * 264;
        unsigned short v = 0;
        if (jj < 256) {
            int gi = (b0 + bb) * 256 + jj;
            v = f2bf(out[OFF_MU + gi] + __expf(0.5f * out[OFF_LV + gi]) * znoise[gi]);
        }
        hs[0][bb][jj] = v;
    }
    if (tid < 256) xs[0][tid >> 4][tid & 15] = 0;

    float hreg[4];
    #pragma unroll
    for (int r = 0; r < 4; r++) {
        int gi = (b0 + quad * 4 + r) * 256 + j;
        hreg[r] = out[OFF_MU + gi] + __expf(0.5f * out[OFF_LV + gi]) * znoise[gi];
    }

    // preload r/z W_hh fragments (loop-invariant, 64 VGPRs)
    const size_t whh_off = (size_t)p * 768 * 256;
    bf16x8 w_r[8], w_z[8];
    #pragma unroll
    for (int k0 = 0; k0 < 8; k0++) {
        const size_t o_r = whh_off + (size_t)(j)       * 256 + k0 * 32 + quad * 8;
        const size_t o_z = whh_off + (size_t)(256 + j) * 256 + k0 * 32 + quad * 8;
        if (WS) {
            w_r[k0] = *(const bf16x8*)(Whh_b + o_r);
            w_z[k0] = *(const bf16x8*)(Whh_b + o_z);
        } else {
            w_r[k0] = pack8(Whh_f + o_r);
            w_z[k0] = pack8(Whh_f + o_z);
        }
    }
    // n-gate weight base (streamed per step)
    const unsigned short* wnb = Whh_b + whh_off + (size_t)(512 + j) * 256 + quad * 8;
    const float*          wnf = Whh_f + whh_off + (size_t)(512 + j) * 256 + quad * 8;

    __syncthreads();

    const float blin_v = blin[p];
    const float b_r  = bR[j], b_z = bZ[j], b_in = bIN[j], b_hn = bHN[j];
    const float wl   = wlin_s[j];
    const bf16x8 ZERO8 = {0, 0, 0, 0, 0, 0, 0, 0};

    for (int t = 0; t < 100; t++) {
        const int cur = t & 1, nxt = cur ^ 1;
        f32x4 acc_r  = {0,0,0,0};
        f32x4 acc_z  = {0,0,0,0};
        f32x4 acc_in = {0,0,0,0};
        f32x4 acc_hn = {0,0,0,0};

        // x part (K=16 zero-padded)
        {
            bf16x8 a, br, bz, bn;
            if (quad < 2) {
                a  = *(const bf16x8*)&xs[cur][ncol][quad * 8];
                br = *(const bf16x8*)&wih_s[j][quad * 8];
                bz = *(const bf16x8*)&wih_s[256 + j][quad * 8];
                bn = *(const bf16x8*)&wih_s[512 + j][quad * 8];
            } else {
                a = ZERO8; br = bz = bn = ZERO8;
            }
            acc_r  = MFMA(a, br, acc_r);
            acc_z  = MFMA(a, bz, acc_z);
            acc_in = MFMA(a, bn, acc_in);
        }
        // h part: r/z weights from registers, n streamed (2-deep pipeline)
        bf16x8 bn_cur = WS ? *(const bf16x8*)(wnb) : pack8(wnf);
        #pragma unroll
        for (int k0 = 0; k0 < 8; k0++) {
            bf16x8 bn_nxt;
            if (k0 < 7)
                bn_nxt = WS ? *(const bf16x8*)(wnb + (k0 + 1) * 32)
                            : pack8(wnf + (k0 + 1) * 32);
            bf16x8 a = *(const bf16x8*)&hs[cur][ncol][k0 * 32 + quad * 8];
            acc_r  = MFMA(a, w_r[k0], acc_r);
            acc_z  = MFMA(a, w_z[k0], acc_z);
            acc_hn = MFMA(a, bn_cur, acc_hn);
            bn_cur = bn_nxt;
        }

        // gates + state update
        float pv[4];
        #pragma unroll
        for (int r = 0; r < 4; r++) {
            float rg = sigm(acc_r[r] + b_r);
            float zg = sigm(acc_z[r] + b_z);
            float nn = tanh_fast(acc_in[r] + b_in + rg * (acc_hn[r] + b_hn));
            float hv = (1.f - zg) * nn + zg * hreg[r];
            hreg[r] = hv;
            pv[r] = fmaxf(hv, 0.f) * wl;
        }
        // reduce across 16 ncol lanes
        #pragma unroll
        for (int r = 0; r < 4; r++) {
            float v = pv[r];
            v += __shfl_xor(v, 1, 64);
            v += __shfl_xor(v, 2, 64);
            v += __shfl_xor(v, 4, 64);
            v += __shfl_xor(v, 8, 64);
            pv[r] = v;
        }

        // writes into nxt buffers (disjoint from cur)
        #pragma unroll
        for (int r = 0; r < 4; r++)
            hs[nxt][quad * 4 + r][j] = f2bf_fast(hreg[r]);
        if (ncol == 0) {
            #pragma unroll
            for (int r = 0; r < 4; r++)
                predw[cur][wave][quad * 4 + r] = pv[r];
        }
        // late x-gather for t+1
        if (tid < 256) {
            int gb = tid >> 4, gk = tid & 15;
            unsigned short v = 0;
            if (t < 99) v = f2bf_fast(X[(size_t)((b0 + gb) * 110 + (10 + t)) * 64 + conn_s[gk]]);
            xs[nxt][gb][gk] = v;
        }

        __syncthreads();   // orders: cur reads & nxt/predw[cur] writes

        if (tid < 16) {
            float s = blin_v;
            #pragma unroll
            for (int w = 0; w < 16; w++) s += predw[cur][w][tid];
            out[(size_t)(p * 64 + b0 + tid) * 100 + t] = s;
        }
    }
}

// ---------------------------------------------------------------------------
extern "C" void kernel_launch(void* const* d_in, const int* in_sizes, int n_in,
                              void* d_out, int out_size, void* d_ws, size_t ws_size,
                              hipStream_t stream) {
    const float* X      = (const float*)d_in[0];
    const int*   conn   = (const int*)d_in[1];
    const float* Wihl   = (const float*)d_in[2];
    const float* Whhl   = (const float*)d_in[3];
    const float* bihl   = (const float*)d_in[4];
    const float* bhhl   = (const float*)d_in[5];
    const float* Wih1   = (const float*)d_in[6];
    // d_in[7] = W_hh_1 unused: gru_1's h0 is 0, so gh reduces to b_hh_1
    const float* bih1   = (const float*)d_in[8];
    const float* bhh1   = (const float*)d_in[9];
    const float* Wmu    = (const float*)d_in[10];
    const float* bmu    = (const float*)d_in[11];
    const float* Wstd   = (const float*)d_in[12];
    const float* bstd   = (const float*)d_in[13];
    const float* Wmean  = (const float*)d_in[14];
    const float* bmean  = (const float*)d_in[15];
    const float* Wdisp  = (const float*)d_in[16];
    const float* bdisp  = (const float*)d_in[17];
    const float* Wihn   = (const float*)d_in[18];
    const float* Whhn   = (const float*)d_in[19];
    const float* bihn   = (const float*)d_in[20];
    const float* bhhn   = (const float*)d_in[21];
    const float* Wlin   = (const float*)d_in[22];
    const float* blin   = (const float*)d_in[23];
    const float* znoise = (const float*)d_in[24];

    float* out = (float*)d_out;
    unsigned short* ws = (unsigned short*)d_ws;

    const bool use_ws = (ws_size >= (size_t)WS_TOTAL * 2);

    if (use_ws) {
        const int total4 = CVT_N1 + CVT_N2;
        cvt_all_kernel<<<(total4 + 255) / 256, 256, 0, stream>>>(
            Whhn, Whhl, Wihl, Wih1, Wmu, Wstd, Wmean, Wdisp, ws);
        encoder_mfma<true><<<4, 512, 0, stream>>>(
            X, Wihl, Whhl, bihl, bhhl, Wih1, bih1, bhh1,
            Wmu, bmu, Wstd, bstd, Wmean, bmean, Wdisp, bdisp, ws, out);
        nets_kernel<true><<<dim3(64, 4), 1024, 0, stream>>>(
            X, conn, Wihn, Whhn, ws + OFS_WHHN,
            bihn, bhhn, Wlin, blin, znoise, out);
    } else {
        encoder_mfma<false><<<4, 512, 0, stream>>>(
            X, Wihl, Whhl, bihl, bhhl, Wih1, bih1, bhh1,
            Wmu, bmu, Wstd, bstd, Wmean, bmean, Wdisp, bdisp,
            (const unsigned short*)nullptr, out);
        nets_kernel<false><<<dim3(64, 4), 1024, 0, stream>>>(
            X, conn, Wihn, Whhn, (const unsigned short*)nullptr,
            bihn, bhhn, Wlin, blin, znoise, out);
    }
}

// Round 15
// 716.743 us; speedup vs baseline: 3.2337x; 1.0011x over previous
//
#include <hip/hip_runtime.h>

// ---------------------------------------------------------------------------
// GRANGER — R15.
// R14 post-mortem: occupancy goal reached (44%) but launch_bounds(1024,1) is
// degenerate (k=0.25 blocks/CU) -> compiler self-selected a 128-total
// VGPR+AGPR budget while the kernel needed ~135 -> moderate spill
// (FETCH 25->230 MB) ate the gain. R15: launch_bounds(1024,4) = exactly
// 1 block/CU (cap 128 total) + shave ~10 regs (1-deep n-gate window).
// Nets: 1024 thr = 16 waves, wave owns ONE 16-col j-slice; w_r/w_z
// register/AGPR-resident (64), n-gate streamed from L2, rcpf gates,
// ping-pong LDS, single barrier/step, late x-gather.
// Encoder (4x512) / cvt unchanged.
// Output layout (fp32): pred[P,B,L,1] | log_var[B,H] | mu[B,H] | mean_[B,P]
// | disp_[B,P]
// ---------------------------------------------------------------------------

#define OFF_LV   409600
#define OFF_MU   425984
#define OFF_MEAN 442368
#define OFF_DISP 446464

// d_ws bf16 bank offsets (elements)
#define OFS_WHHN  0
#define OFS_WHHL  12582912
#define OFS_WIHL  12779520
#define OFS_WIH1  12828672
#define OFS_WMU   13025280
#define OFS_WSTD  13090816
#define OFS_WMEAN 13156352
#define OFS_WDISP 13172736
#define WS_TOTAL  13189120   // elems; *2 bytes = 26,378,240

typedef __attribute__((ext_vector_type(8))) short  bf16x8;
typedef __attribute__((ext_vector_type(4))) float  f32x4;

__device__ __forceinline__ float bf2f(unsigned short u) {
    union { unsigned int i; float f; } v; v.i = ((unsigned int)u) << 16; return v.f;
}
__device__ __forceinline__ unsigned short f2bf(float f) {
    union { float f; unsigned int i; } v; v.f = f;
    unsigned int x = v.i;
    return (unsigned short)((x + 0x7FFFu + ((x >> 16) & 1u)) >> 16);
}
__device__ __forceinline__ unsigned short f2bf_fast(float f) {
    return (unsigned short)((__float_as_uint(f) + 0x8000u) >> 16);
}
__device__ __forceinline__ bf16x8 pack8(const float* pf) {
    union { unsigned int u[4]; bf16x8 v; } r;
    const float4 a = *(const float4*)pf;
    const float4 b = *(const float4*)(pf + 4);
    r.u[0] = ((__float_as_uint(a.x) + 0x8000u) >> 16) | ((__float_as_uint(a.y) + 0x8000u) & 0xFFFF0000u);
    r.u[1] = ((__float_as_uint(a.z) + 0x8000u) >> 16) | ((__float_as_uint(a.w) + 0x8000u) & 0xFFFF0000u);
    r.u[2] = ((__float_as_uint(b.x) + 0x8000u) >> 16) | ((__float_as_uint(b.y) + 0x8000u) & 0xFFFF0000u);
    r.u[3] = ((__float_as_uint(b.z) + 0x8000u) >> 16) | ((__float_as_uint(b.w) + 0x8000u) & 0xFFFF0000u);
    return r.v;
}
// rcpf-based, inf-safe
__device__ __forceinline__ float sigm(float x) {
    return __builtin_amdgcn_rcpf(1.0f + __expf(-x));
}
__device__ __forceinline__ float tanh_fast(float x) {
    return 2.0f * __builtin_amdgcn_rcpf(1.0f + __expf(-2.0f * x)) - 1.0f;
}

#define MFMA(a, b, c) __builtin_amdgcn_mfma_f32_16x16x32_bf16((a), (b), (c), 0, 0, 0)

// ---------------------------------------------------------------------------
// cvt_all: all fp32 weight tensors -> bf16 bank in d_ws.
// ---------------------------------------------------------------------------
#define CVT_N1 3145728   // 12582912/4
#define CVT_N2 151552
__global__ __launch_bounds__(256) void cvt_all_kernel(
    const float* __restrict__ Whhn,
    const float* __restrict__ Whhl, const float* __restrict__ Wihl,
    const float* __restrict__ Wih1, const float* __restrict__ Wmu,
    const float* __restrict__ Wstd, const float* __restrict__ Wmean,
    const float* __restrict__ Wdisp, unsigned short* __restrict__ ws)
{
    int i4 = blockIdx.x * 256 + threadIdx.x;
    const float* src;
    int idx, dst4;
    if (i4 < CVT_N1) {
        src = Whhn; idx = i4; dst4 = i4;
    } else {
        int k = i4 - CVT_N1;
        if (k >= CVT_N2) return;
        int base;
        if      (k <  49152) { src = Whhl;  base = 0; }
        else if (k <  61440) { src = Wihl;  base = 49152; }
        else if (k < 110592) { src = Wih1;  base = 61440; }
        else if (k < 126976) { src = Wmu;   base = 110592; }
        else if (k < 143360) { src = Wstd;  base = 126976; }
        else if (k < 147456) { src = Wmean; base = 143360; }
        else                 { src = Wdisp; base = 147456; }
        idx = k - base; dst4 = OFS_WHHL / 4 + k;
    }
    float4 a = ((const float4*)src)[idx];
    ushort4 r;
    r.x = f2bf_fast(a.x); r.y = f2bf_fast(a.y);
    r.z = f2bf_fast(a.z); r.w = f2bf_fast(a.w);
    ((ushort4*)ws)[dst4] = r;
}

// ---------------------------------------------------------------------------
// Encoder: 4 blocks (16 batch rows each) x 512 thr = 8 waves (R12, unchanged).
// ---------------------------------------------------------------------------
template <bool WS>
__global__ __launch_bounds__(512, 2) void encoder_mfma(
    const float* __restrict__ X,
    const float* __restrict__ Wihl_f, const float* __restrict__ Whhl_f,
    const float* __restrict__ bihl,   const float* __restrict__ bhhl,
    const float* __restrict__ Wih1_f, const float* __restrict__ bih1,
    const float* __restrict__ bhh1,
    const float* __restrict__ Wmu_f,  const float* __restrict__ bmu,
    const float* __restrict__ Wstd_f, const float* __restrict__ bstd,
    const float* __restrict__ Wmean_f,const float* __restrict__ bmean,
    const float* __restrict__ Wdisp_f,const float* __restrict__ bdisp,
    const unsigned short* __restrict__ ws,
    float* __restrict__ out)
{
    const int b0   = blockIdx.x * 16;
    const int tid  = threadIdx.x;
    const int wave = tid >> 6;
    const int lane = tid & 63;
    const int quad = lane >> 4;
    const int ncol = lane & 15;
    const int j0   = wave * 32 + ncol;
    const int j1   = j0 + 16;

    __shared__ __align__(16) unsigned short hs[2][16][264];
    __shared__ __align__(16) unsigned short xs[2][16][72];
    __shared__ float bR[256], bZ[256], bIN[256], bHN[256];
    __shared__ float b1R[256], b1Z[256], b1IN[256], b1HN[256];

    for (int i = tid; i < 256; i += 512) {
        bR[i]   = bihl[i]       + bhhl[i];
        bZ[i]   = bihl[256 + i] + bhhl[256 + i];
        bIN[i]  = bihl[512 + i];
        bHN[i]  = bhhl[512 + i];
        b1R[i]  = bih1[i]       + bhh1[i];
        b1Z[i]  = bih1[256 + i] + bhh1[256 + i];
        b1IN[i] = bih1[512 + i];
        b1HN[i] = bhh1[512 + i];
    }
    for (int i = tid; i < 16 * 264; i += 512)
        (&hs[0][0][0])[i] = 0;                       // h0 = 0
    for (int i = tid; i < 1024; i += 512) {
        int b = i >> 6, f = i & 63;
        xs[0][b][f] = f2bf_fast(X[((b0 + b) * 110 + 0) * 64 + f]);
    }

    float hreg[2][4];
    #pragma unroll
    for (int s = 0; s < 2; s++)
        #pragma unroll
        for (int r = 0; r < 4; r++) hreg[s][r] = 0.f;

    const unsigned short* wsWIHL = ws + OFS_WIHL;
    const unsigned short* wsWHHL = ws + OFS_WHHL;
    const unsigned short* wsWIH1 = ws + OFS_WIH1;
    const unsigned short* wsWMU  = ws + OFS_WMU;
    const unsigned short* wsWSTD = ws + OFS_WSTD;
    const unsigned short* wsWMEAN= ws + OFS_WMEAN;
    const unsigned short* wsWDISP= ws + OFS_WDISP;

    __syncthreads();

    // ---- gru_left: 10 MFMA steps ----
    for (int t = 0; t < 10; t++) {
        const int cur = t & 1, nxt = cur ^ 1;
        f32x4 acc_r[2]  = {{0,0,0,0},{0,0,0,0}};
        f32x4 acc_z[2]  = {{0,0,0,0},{0,0,0,0}};
        f32x4 acc_in[2] = {{0,0,0,0},{0,0,0,0}};
        f32x4 acc_hn[2] = {{0,0,0,0},{0,0,0,0}};

        #pragma unroll
        for (int ks = 0; ks < 2; ks++) {
            const int ko = ks * 32 + quad * 8;
            bf16x8 a = *(const bf16x8*)&xs[cur][ncol][ks * 32 + quad * 8];
            #pragma unroll
            for (int s = 0; s < 2; s++) {
                const int j = s ? j1 : j0;
                bf16x8 br = WS ? *(const bf16x8*)(wsWIHL + (j)       * 64 + ko) : pack8(Wihl_f + (j)       * 64 + ko);
                bf16x8 bz = WS ? *(const bf16x8*)(wsWIHL + (256 + j) * 64 + ko) : pack8(Wihl_f + (256 + j) * 64 + ko);
                bf16x8 bn = WS ? *(const bf16x8*)(wsWIHL + (512 + j) * 64 + ko) : pack8(Wihl_f + (512 + j) * 64 + ko);
                acc_r[s]  = MFMA(a, br, acc_r[s]);
                acc_z[s]  = MFMA(a, bz, acc_z[s]);
                acc_in[s] = MFMA(a, bn, acc_in[s]);
            }
        }
        #pragma unroll 2
        for (int ks = 0; ks < 8; ks++) {
            const int ko = ks * 32 + quad * 8;
            bf16x8 a = *(const bf16x8*)&hs[cur][ncol][ks * 32 + quad * 8];
            #pragma unroll
            for (int s = 0; s < 2; s++) {
                const int j = s ? j1 : j0;
                bf16x8 br = WS ? *(const bf16x8*)(wsWHHL + (size_t)(j)       * 256 + ko) : pack8(Whhl_f + (size_t)(j)       * 256 + ko);
                bf16x8 bz = WS ? *(const bf16x8*)(wsWHHL + (size_t)(256 + j) * 256 + ko) : pack8(Whhl_f + (size_t)(256 + j) * 256 + ko);
                bf16x8 bn = WS ? *(const bf16x8*)(wsWHHL + (size_t)(512 + j) * 256 + ko) : pack8(Whhl_f + (size_t)(512 + j) * 256 + ko);
                acc_r[s]  = MFMA(a, br, acc_r[s]);
                acc_z[s]  = MFMA(a, bz, acc_z[s]);
                acc_hn[s] = MFMA(a, bn, acc_hn[s]);
            }
        }
        #pragma unroll
        for (int s = 0; s < 2; s++) {
            const int j = s ? j1 : j0;
            #pragma unroll
            for (int r = 0; r < 4; r++) {
                float rg = sigm(acc_r[s][r] + bR[j]);
                float zg = sigm(acc_z[s][r] + bZ[j]);
                float nn = tanh_fast(acc_in[s][r] + bIN[j] + rg * (acc_hn[s][r] + bHN[j]));
                float hv = (1.f - zg) * nn + zg * hreg[s][r];
                hreg[s][r] = hv;
                hs[nxt][quad * 4 + r][j] = f2bf(hv);
            }
        }
        if (t < 9)
            for (int i = tid; i < 1024; i += 512) {
                int b = i >> 6, f = i & 63;
                xs[nxt][b][f] = f2bf_fast(X[((b0 + b) * 110 + (t + 1)) * 64 + f]);
            }
        __syncthreads();
    }

    // ---- gru_1 ----
    {
        f32x4 acc_r[2]  = {{0,0,0,0},{0,0,0,0}};
        f32x4 acc_z[2]  = {{0,0,0,0},{0,0,0,0}};
        f32x4 acc_in[2] = {{0,0,0,0},{0,0,0,0}};
        #pragma unroll 2
        for (int ks = 0; ks < 8; ks++) {
            const int ko = ks * 32 + quad * 8;
            bf16x8 a = *(const bf16x8*)&hs[0][ncol][ks * 32 + quad * 8];
            #pragma unroll
            for (int s = 0; s < 2; s++) {
                const int j = s ? j1 : j0;
                bf16x8 br = WS ? *(const bf16x8*)(wsWIH1 + (size_t)(j)       * 256 + ko) : pack8(Wih1_f + (size_t)(j)       * 256 + ko);
                bf16x8 bz = WS ? *(const bf16x8*)(wsWIH1 + (size_t)(256 + j) * 256 + ko) : pack8(Wih1_f + (size_t)(256 + j) * 256 + ko);
                bf16x8 bn = WS ? *(const bf16x8*)(wsWIH1 + (size_t)(512 + j) * 256 + ko) : pack8(Wih1_f + (size_t)(512 + j) * 256 + ko);
                acc_r[s]  = MFMA(a, br, acc_r[s]);
                acc_z[s]  = MFMA(a, bz, acc_z[s]);
                acc_in[s] = MFMA(a, bn, acc_in[s]);
            }
        }
        #pragma unroll
        for (int s = 0; s < 2; s++) {
            const int j = s ? j1 : j0;
            #pragma unroll
            for (int r = 0; r < 4; r++) {
                float rg = sigm(acc_r[s][r] + b1R[j]);
                float zg = sigm(acc_z[s][r] + b1Z[j]);
                float nn = tanh_fast(acc_in[s][r] + b1IN[j] + rg * b1HN[j]);
                float hv = (1.f - zg) * nn;
                hs[1][quad * 4 + r][j] = f2bf(hv);
            }
        }
        __syncthreads();
    }

    // ---- heads ----
    {
        f32x4 acc_mu[2] = {{0,0,0,0},{0,0,0,0}};
        f32x4 acc_lv[2] = {{0,0,0,0},{0,0,0,0}};
        f32x4 acc_md[2] = {{0,0,0,0},{0,0,0,0}};
        const bool do_mean = (wave < 2), do_disp = (wave >= 2 && wave < 4);
        const int jm0 = (wave & 1) * 32 + ncol, jm1 = jm0 + 16;

        #pragma unroll 2
        for (int ks = 0; ks < 8; ks++) {
            const int ko = ks * 32 + quad * 8;
            bf16x8 a = *(const bf16x8*)&hs[1][ncol][ks * 32 + quad * 8];
            #pragma unroll
            for (int s = 0; s < 2; s++) {
                const int j = s ? j1 : j0;
                bf16x8 bmu8 = WS ? *(const bf16x8*)(wsWMU  + (size_t)j * 256 + ko) : pack8(Wmu_f  + (size_t)j * 256 + ko);
                bf16x8 blv8 = WS ? *(const bf16x8*)(wsWSTD + (size_t)j * 256 + ko) : pack8(Wstd_f + (size_t)j * 256 + ko);
                acc_mu[s] = MFMA(a, bmu8, acc_mu[s]);
                acc_lv[s] = MFMA(a, blv8, acc_lv[s]);
                if (do_mean || do_disp) {
                    const int jm = s ? jm1 : jm0;
                    bf16x8 md8;
                    if (do_mean) md8 = WS ? *(const bf16x8*)(wsWMEAN + (size_t)jm * 256 + ko) : pack8(Wmean_f + (size_t)jm * 256 + ko);
                    else         md8 = WS ? *(const bf16x8*)(wsWDISP + (size_t)jm * 256 + ko) : pack8(Wdisp_f + (size_t)jm * 256 + ko);
                    acc_md[s] = MFMA(a, md8, acc_md[s]);
                }
            }
        }
        #pragma unroll
        for (int s = 0; s < 2; s++) {
            const int j = s ? j1 : j0;
            const float bmu_v = bmu[j], blv_v = bstd[j];
            #pragma unroll
            for (int r = 0; r < 4; r++) {
                int b = b0 + quad * 4 + r;
                out[OFF_MU + b * 256 + j] = acc_mu[s][r] + bmu_v;
                out[OFF_LV + b * 256 + j] = acc_lv[s][r] + blv_v;
            }
        }
        if (do_mean) {
            #pragma unroll
            for (int s = 0; s < 2; s++) {
                const int jm = s ? jm1 : jm0;
                const float bm = bmean[jm];
                #pragma unroll
                for (int r = 0; r < 4; r++) {
                    int b = b0 + quad * 4 + r;
                    out[OFF_MEAN + b * 64 + jm] =
                        fminf(fmaxf(__expf(acc_md[s][r] + bm), 1e-5f), 1e6f);
                }
            }
        } else if (do_disp) {
            #pragma unroll
            for (int s = 0; s < 2; s++) {
                const int jm = s ? jm1 : jm0;
                const float bd = bdisp[jm];
                #pragma unroll
                for (int r = 0; r < 4; r++) {
                    int b = b0 + quad * 4 + r;
                    float v = acc_md[s][r] + bd;
                    float sp = (v > 20.f) ? v : log1pf(__expf(v));
                    out[OFF_DISP + b * 64 + jm] = fminf(fmaxf(sp, 1e-4f), 1e4f);
                }
            }
        }
    }
}

// ---------------------------------------------------------------------------
// Nets: grid (p=64, btile=4 of 16 rows) = 256 blocks, 1024 thr = 16 waves,
// __launch_bounds__(1024,4) = exactly 1 block/CU -> 128 VGPR+AGPR/wave cap.
// Wave owns ONE 16-col j-slice: w_r/w_z resident (~64, mostly AGPR),
// n-gate streamed from L2 (1-deep window, compiler pipelines within budget).
// rcpf gates, ping-pong LDS, single barrier/step, late x-gather.
// ---------------------------------------------------------------------------
template <bool WS>
__global__ __launch_bounds__(1024, 4) void nets_kernel(
    const float*          __restrict__ X,
    const int*            __restrict__ conn,
    const float*          __restrict__ Wih,
    const float*          __restrict__ Whh_f,
    const unsigned short* __restrict__ Whh_b,
    const float*          __restrict__ bih,
    const float*          __restrict__ bhh,
    const float*          __restrict__ Wlin,
    const float*          __restrict__ blin,
    const float*          __restrict__ znoise,
    float*                __restrict__ out)
{
    const int p    = blockIdx.x;
    const int b0   = blockIdx.y * 16;
    const int tid  = threadIdx.x;
    const int wave = tid >> 6;       // 0..15
    const int lane = tid & 63;
    const int quad = lane >> 4;
    const int ncol = lane & 15;
    const int j    = wave * 16 + ncol;

    __shared__ __align__(16) unsigned short hs[2][16][264];
    __shared__ __align__(16) unsigned short xs[2][16][16];
    __shared__ __align__(16) unsigned short wih_s[768][16];
    __shared__ float bR[256], bZ[256], bIN[256], bHN[256], wlin_s[256];
    __shared__ float predw[2][16][16];
    __shared__ int   conn_s[16];

    for (int i = tid; i < 768 * 16; i += 1024)
        (&wih_s[0][0])[i] = f2bf_fast(Wih[p * 768 * 16 + i]);
    for (int i = tid; i < 256; i += 1024) {
        bR[i]  = bih[p * 768 + i]       + bhh[p * 768 + i];
        bZ[i]  = bih[p * 768 + 256 + i] + bhh[p * 768 + 256 + i];
        bIN[i] = bih[p * 768 + 512 + i];
        bHN[i] = bhh[p * 768 + 512 + i];
        wlin_s[i] = Wlin[p * 256 + i];
    }
    if (tid < 16) conn_s[tid] = conn[p * 16 + tid];

    for (int i = tid; i < 16 * 264; i += 1024) {
        int bb = i / 264, jj = i - bb * 264;
        unsigned short v = 0;
        if (jj < 256) {
            int gi = (b0 + bb) * 256 + jj;
            v = f2bf(out[OFF_MU + gi] + __expf(0.5f * out[OFF_LV + gi]) * znoise[gi]);
        }
        hs[0][bb][jj] = v;
    }
    if (tid < 256) xs[0][tid >> 4][tid & 15] = 0;

    float hreg[4];
    #pragma unroll
    for (int r = 0; r < 4; r++) {
        int gi = (b0 + quad * 4 + r) * 256 + j;
        hreg[r] = out[OFF_MU + gi] + __expf(0.5f * out[OFF_LV + gi]) * znoise[gi];
    }

    // preload r/z W_hh fragments (loop-invariant)
    const size_t whh_off = (size_t)p * 768 * 256;
    bf16x8 w_r[8], w_z[8];
    #pragma unroll
    for (int k0 = 0; k0 < 8; k0++) {
        const size_t o_r = whh_off + (size_t)(j)       * 256 + k0 * 32 + quad * 8;
        const size_t o_z = whh_off + (size_t)(256 + j) * 256 + k0 * 32 + quad * 8;
        if (WS) {
            w_r[k0] = *(const bf16x8*)(Whh_b + o_r);
            w_z[k0] = *(const bf16x8*)(Whh_b + o_z);
        } else {
            w_r[k0] = pack8(Whh_f + o_r);
            w_z[k0] = pack8(Whh_f + o_z);
        }
    }
    // n-gate weight base (streamed per step)
    const unsigned short* wnb = Whh_b + whh_off + (size_t)(512 + j) * 256 + quad * 8;
    const float*          wnf = Whh_f + whh_off + (size_t)(512 + j) * 256 + quad * 8;

    __syncthreads();

    const float blin_v = blin[p];
    const float b_r  = bR[j], b_z = bZ[j], b_in = bIN[j], b_hn = bHN[j];
    const float wl   = wlin_s[j];
    const bf16x8 ZERO8 = {0, 0, 0, 0, 0, 0, 0, 0};

    for (int t = 0; t < 100; t++) {
        const int cur = t & 1, nxt = cur ^ 1;
        f32x4 acc_r  = {0,0,0,0};
        f32x4 acc_z  = {0,0,0,0};
        f32x4 acc_in = {0,0,0,0};
        f32x4 acc_hn = {0,0,0,0};

        // x part (K=16 zero-padded)
        {
            bf16x8 a, br, bz, bn;
            if (quad < 2) {
                a  = *(const bf16x8*)&xs[cur][ncol][quad * 8];
                br = *(const bf16x8*)&wih_s[j][quad * 8];
                bz = *(const bf16x8*)&wih_s[256 + j][quad * 8];
                bn = *(const bf16x8*)&wih_s[512 + j][quad * 8];
            } else {
                a = ZERO8; br = bz = bn = ZERO8;
            }
            acc_r  = MFMA(a, br, acc_r);
            acc_z  = MFMA(a, bz, acc_z);
            acc_in = MFMA(a, bn, acc_in);
        }
        // h part: r/z weights resident, n streamed (1-deep window)
        #pragma unroll
        for (int k0 = 0; k0 < 8; k0++) {
            bf16x8 bn = WS ? *(const bf16x8*)(wnb + k0 * 32) : pack8(wnf + k0 * 32);
            bf16x8 a  = *(const bf16x8*)&hs[cur][ncol][k0 * 32 + quad * 8];
            acc_r  = MFMA(a, w_r[k0], acc_r);
            acc_z  = MFMA(a, w_z[k0], acc_z);
            acc_hn = MFMA(a, bn, acc_hn);
        }

        // gates + state update
        float pv[4];
        #pragma unroll
        for (int r = 0; r < 4; r++) {
            float rg = sigm(acc_r[r] + b_r);
            float zg = sigm(acc_z[r] + b_z);
            float nn = tanh_fast(acc_in[r] + b_in + rg * (acc_hn[r] + b_hn));
            float hv = (1.f - zg) * nn + zg * hreg[r];
            hreg[r] = hv;
            pv[r] = fmaxf(hv, 0.f) * wl;
        }
        // reduce across 16 ncol lanes
        #pragma unroll
        for (int r = 0; r < 4; r++) {
            float v = pv[r];
            v += __shfl_xor(v, 1, 64);
            v += __shfl_xor(v, 2, 64);
            v += __shfl_xor(v, 4, 64);
            v += __shfl_xor(v, 8, 64);
            pv[r] = v;
        }

        // writes into nxt buffers (disjoint from cur)
        #pragma unroll
        for (int r = 0; r < 4; r++)
            hs[nxt][quad * 4 + r][j] = f2bf_fast(hreg[r]);
        if (ncol == 0) {
            #pragma unroll
            for (int r = 0; r < 4; r++)
                predw[cur][wave][quad * 4 + r] = pv[r];
        }
        // late x-gather for t+1
        if (tid < 256) {
            int gb = tid >> 4, gk = tid & 15;
            unsigned short v = 0;
            if (t < 99) v = f2bf_fast(X[(size_t)((b0 + gb) * 110 + (10 + t)) * 64 + conn_s[gk]]);
            xs[nxt][gb][gk] = v;
        }

        __syncthreads();   // orders: cur reads & nxt/predw[cur] writes

        if (tid < 16) {
            float s = blin_v;
            #pragma unroll
            for (int w = 0; w < 16; w++) s += predw[cur][w][tid];
            out[(size_t)(p * 64 + b0 + tid) * 100 + t] = s;
        }
    }
}

// ---------------------------------------------------------------------------
extern "C" void kernel_launch(void* const* d_in, const int* in_sizes, int n_in,
                              void* d_out, int out_size, void* d_ws, size_t ws_size,
                              hipStream_t stream) {
    const float* X      = (const float*)d_in[0];
    const int*   conn   = (const int*)d_in[1];
    const float* Wihl   = (const float*)d_in[2];
    const float* Whhl   = (const float*)d_in[3];
    const float* bihl   = (const float*)d_in[4];
    const float* bhhl   = (const float*)d_in[5];
    const float* Wih1   = (const float*)d_in[6];
    // d_in[7] = W_hh_1 unused: gru_1's h0 is 0, so gh reduces to b_hh_1
    const float* bih1   = (const float*)d_in[8];
    const float* bhh1   = (const float*)d_in[9];
    const float* Wmu    = (const float*)d_in[10];
    const float* bmu    = (const float*)d_in[11];
    const float* Wstd   = (const float*)d_in[12];
    const float* bstd   = (const float*)d_in[13];
    const float* Wmean  = (const float*)d_in[14];
    const float* bmean  = (const float*)d_in[15];
    const float* Wdisp  = (const float*)d_in[16];
    const float* bdisp  = (const float*)d_in[17];
    const float* Wihn   = (const float*)d_in[18];
    const float* Whhn   = (const float*)d_in[19];
    const float* bihn   = (const float*)d_in[20];
    const float* bhhn   = (const float*)d_in[21];
    const float* Wlin   = (const float*)d_in[22];
    const float* blin   = (const float*)d_in[23];
    const float* znoise = (const float*)d_in[24];

    float* out = (float*)d_out;
    unsigned short* ws = (unsigned short*)d_ws;

    const bool use_ws = (ws_size >= (size_t)WS_TOTAL * 2);

    if (use_ws) {
        const int total4 = CVT_N1 + CVT_N2;
        cvt_all_kernel<<<(total4 + 255) / 256, 256, 0, stream>>>(
            Whhn, Whhl, Wihl, Wih1, Wmu, Wstd, Wmean, Wdisp, ws);
        encoder_mfma<true><<<4, 512, 0, stream>>>(
            X, Wihl, Whhl, bihl, bhhl, Wih1, bih1, bhh1,
            Wmu, bmu, Wstd, bstd, Wmean, bmean, Wdisp, bdisp, ws, out);
        nets_kernel<true><<<dim3(64, 4), 1024, 0, stream>>>(
            X, conn, Wihn, Whhn, ws + OFS_WHHN,
            bihn, bhhn, Wlin, blin, znoise, out);
    } else {
        encoder_mfma<false><<<4, 512, 0, stream>>>(
            X, Wihl, Whhl, bihl, bhhl, Wih1, bih1, bhh1,
            Wmu, bmu, Wstd, bstd, Wmean, bmean, Wdisp, bdisp,
            (const unsigned short*)nullptr, out);
        nets_kernel<false><<<dim3(64, 4), 1024, 0, stream>>>(
            X, conn, Wihn, Whhn, (const unsigned short*)nullptr,
            bihn, bhhn, Wlin, blin, znoise, out);
    }
}

// Round 16
// 524.068 us; speedup vs baseline: 4.4226x; 1.3677x over previous
//
#include <hip/hip_runtime.h>

// ---------------------------------------------------------------------------
// GRANGER — R16.
// 1) nets reverted to R11-exact structure (311 us known-good: 512 thr,
//    launch_bounds(512,2), 2 j-slices/wave, all 3 gates register/AGPR-
//    resident under the 256/wave budget). R13-R15 proved 16-wave blocks
//    (128-reg ceiling) always spill this kernel.
// 2) encoder: loop-invariant weights hoisted out of the 10-step loop —
//    W_hh_left register-resident (192 regs, launch_bounds(512,1): 512-reg
//    budget, no spill; only 4 blocks so occupancy is moot), W_ih_left in
//    LDS (stride 72 to dodge bank conflicts). Steps now have zero global
//    traffic (the ~200 us non-nets residue was L2-latency-bound re-streams).
// 3) cvt kernel dropped — both kernels pack8 from fp32 directly (one less
//    launch, -75 MB traffic; all preloads one-shot).
// Output layout (fp32): pred[P,B,L,1] | log_var[B,H] | mu[B,H] | mean_[B,P]
// | disp_[B,P]
// ---------------------------------------------------------------------------

#define OFF_LV   409600
#define OFF_MU   425984
#define OFF_MEAN 442368
#define OFF_DISP 446464

typedef __attribute__((ext_vector_type(8))) short  bf16x8;
typedef __attribute__((ext_vector_type(4))) float  f32x4;

__device__ __forceinline__ float bf2f(unsigned short u) {
    union { unsigned int i; float f; } v; v.i = ((unsigned int)u) << 16; return v.f;
}
__device__ __forceinline__ unsigned short f2bf(float f) {
    union { float f; unsigned int i; } v; v.f = f;
    unsigned int x = v.i;
    return (unsigned short)((x + 0x7FFFu + ((x >> 16) & 1u)) >> 16);
}
__device__ __forceinline__ unsigned short f2bf_fast(float f) {
    return (unsigned short)((__float_as_uint(f) + 0x8000u) >> 16);
}
__device__ __forceinline__ bf16x8 pack8(const float* pf) {
    union { unsigned int u[4]; bf16x8 v; } r;
    const float4 a = *(const float4*)pf;
    const float4 b = *(const float4*)(pf + 4);
    r.u[0] = ((__float_as_uint(a.x) + 0x8000u) >> 16) | ((__float_as_uint(a.y) + 0x8000u) & 0xFFFF0000u);
    r.u[1] = ((__float_as_uint(a.z) + 0x8000u) >> 16) | ((__float_as_uint(a.w) + 0x8000u) & 0xFFFF0000u);
    r.u[2] = ((__float_as_uint(b.x) + 0x8000u) >> 16) | ((__float_as_uint(b.y) + 0x8000u) & 0xFFFF0000u);
    r.u[3] = ((__float_as_uint(b.z) + 0x8000u) >> 16) | ((__float_as_uint(b.w) + 0x8000u) & 0xFFFF0000u);
    return r.v;
}
// rcpf-based, inf-safe
__device__ __forceinline__ float sigm(float x) {
    return __builtin_amdgcn_rcpf(1.0f + __expf(-x));
}
__device__ __forceinline__ float tanh_fast(float x) {
    return 2.0f * __builtin_amdgcn_rcpf(1.0f + __expf(-2.0f * x)) - 1.0f;
}

#define MFMA(a, b, c) __builtin_amdgcn_mfma_f32_16x16x32_bf16((a), (b), (c), 0, 0, 0)

// ---------------------------------------------------------------------------
// Encoder: 4 blocks (16 batch rows each) x 512 thr = 8 waves.
// Wave owns cols j0 = wave*32+ncol and j1 = j0+16.
// W_hh_left register-resident (preloaded once); W_ih_left in LDS.
// Fragment mapping (HW-verified): A[m=lane&15][k=quad*8+i],
// D[m=quad*4+r][n=ncol].
// ---------------------------------------------------------------------------
__global__ __launch_bounds__(512, 1) void encoder_mfma(
    const float* __restrict__ X,
    const float* __restrict__ Wihl_f, const float* __restrict__ Whhl_f,
    const float* __restrict__ bihl,   const float* __restrict__ bhhl,
    const float* __restrict__ Wih1_f, const float* __restrict__ bih1,
    const float* __restrict__ bhh1,
    const float* __restrict__ Wmu_f,  const float* __restrict__ bmu,
    const float* __restrict__ Wstd_f, const float* __restrict__ bstd,
    const float* __restrict__ Wmean_f,const float* __restrict__ bmean,
    const float* __restrict__ Wdisp_f,const float* __restrict__ bdisp,
    float* __restrict__ out)
{
    const int b0   = blockIdx.x * 16;
    const int tid  = threadIdx.x;
    const int wave = tid >> 6;
    const int lane = tid & 63;
    const int quad = lane >> 4;
    const int ncol = lane & 15;
    const int j0   = wave * 32 + ncol;
    const int j1   = j0 + 16;

    __shared__ __align__(16) unsigned short hs[2][16][264];
    __shared__ __align__(16) unsigned short xs[2][16][72];
    __shared__ __align__(16) unsigned short wihl_s[768][72];  // bf16, pad 64->72
    __shared__ float bR[256], bZ[256], bIN[256], bHN[256];
    __shared__ float b1R[256], b1Z[256], b1IN[256], b1HN[256];

    // stage W_ih_left -> LDS (bf16), 768x64
    for (int i = tid; i < 768 * 64; i += 512) {
        int row = i >> 6, col = i & 63;
        wihl_s[row][col] = f2bf_fast(Wihl_f[i]);
    }
    for (int i = tid; i < 256; i += 512) {
        bR[i]   = bihl[i]       + bhhl[i];
        bZ[i]   = bihl[256 + i] + bhhl[256 + i];
        bIN[i]  = bihl[512 + i];
        bHN[i]  = bhhl[512 + i];
        b1R[i]  = bih1[i]       + bhh1[i];
        b1Z[i]  = bih1[256 + i] + bhh1[256 + i];
        b1IN[i] = bih1[512 + i];
        b1HN[i] = bhh1[512 + i];
    }
    for (int i = tid; i < 16 * 264; i += 512)
        (&hs[0][0][0])[i] = 0;                       // h0 = 0
    for (int i = tid; i < 1024; i += 512) {
        int b = i >> 6, f = i & 63;
        xs[0][b][f] = f2bf_fast(X[((b0 + b) * 110 + 0) * 64 + f]);
    }

    // preload W_hh_left fragments into registers (loop-invariant, 192 regs)
    bf16x8 w_r[2][8], w_z[2][8], w_n[2][8];
    #pragma unroll
    for (int s = 0; s < 2; s++) {
        const int j = s ? j1 : j0;
        #pragma unroll
        for (int k0 = 0; k0 < 8; k0++) {
            const int ko = k0 * 32 + quad * 8;
            w_r[s][k0] = pack8(Whhl_f + (size_t)(j)       * 256 + ko);
            w_z[s][k0] = pack8(Whhl_f + (size_t)(256 + j) * 256 + ko);
            w_n[s][k0] = pack8(Whhl_f + (size_t)(512 + j) * 256 + ko);
        }
    }

    float hreg[2][4];
    #pragma unroll
    for (int s = 0; s < 2; s++)
        #pragma unroll
        for (int r = 0; r < 4; r++) hreg[s][r] = 0.f;

    __syncthreads();

    // ---- gru_left: 10 MFMA steps, zero global traffic ----
    for (int t = 0; t < 10; t++) {
        const int cur = t & 1, nxt = cur ^ 1;
        f32x4 acc_r[2]  = {{0,0,0,0},{0,0,0,0}};
        f32x4 acc_z[2]  = {{0,0,0,0},{0,0,0,0}};
        f32x4 acc_in[2] = {{0,0,0,0},{0,0,0,0}};
        f32x4 acc_hn[2] = {{0,0,0,0},{0,0,0,0}};

        // x part: k = 64 -> 2 k-steps (weights from LDS)
        #pragma unroll
        for (int ks = 0; ks < 2; ks++) {
            const int ko = ks * 32 + quad * 8;
            bf16x8 a = *(const bf16x8*)&xs[cur][ncol][ko];
            #pragma unroll
            for (int s = 0; s < 2; s++) {
                const int j = s ? j1 : j0;
                bf16x8 br = *(const bf16x8*)&wihl_s[j][ko];
                bf16x8 bz = *(const bf16x8*)&wihl_s[256 + j][ko];
                bf16x8 bn = *(const bf16x8*)&wihl_s[512 + j][ko];
                acc_r[s]  = MFMA(a, br, acc_r[s]);
                acc_z[s]  = MFMA(a, bz, acc_z[s]);
                acc_in[s] = MFMA(a, bn, acc_in[s]);
            }
        }
        // h part: weights from registers
        #pragma unroll
        for (int ks = 0; ks < 8; ks++) {
            bf16x8 a = *(const bf16x8*)&hs[cur][ncol][ks * 32 + quad * 8];
            #pragma unroll
            for (int s = 0; s < 2; s++) {
                acc_r[s]  = MFMA(a, w_r[s][ks], acc_r[s]);
                acc_z[s]  = MFMA(a, w_z[s][ks], acc_z[s]);
                acc_hn[s] = MFMA(a, w_n[s][ks], acc_hn[s]);
            }
        }
        // epilogue + state write
        #pragma unroll
        for (int s = 0; s < 2; s++) {
            const int j = s ? j1 : j0;
            #pragma unroll
            for (int r = 0; r < 4; r++) {
                float rg = sigm(acc_r[s][r] + bR[j]);
                float zg = sigm(acc_z[s][r] + bZ[j]);
                float nn = tanh_fast(acc_in[s][r] + bIN[j] + rg * (acc_hn[s][r] + bHN[j]));
                float hv = (1.f - zg) * nn + zg * hreg[s][r];
                hreg[s][r] = hv;
                hs[nxt][quad * 4 + r][j] = f2bf(hv);
            }
        }
        if (t < 9)
            for (int i = tid; i < 1024; i += 512) {
                int b = i >> 6, f = i & 63;
                xs[nxt][b][f] = f2bf_fast(X[((b0 + b) * 110 + (t + 1)) * 64 + f]);
            }
        __syncthreads();
    }
    // h_left in hs[0] (t=9: nxt=0)

    // ---- gru_1: one step, input h_left, h0 = 0 (gh = b_hh_1) ----
    {
        f32x4 acc_r[2]  = {{0,0,0,0},{0,0,0,0}};
        f32x4 acc_z[2]  = {{0,0,0,0},{0,0,0,0}};
        f32x4 acc_in[2] = {{0,0,0,0},{0,0,0,0}};
        #pragma unroll 2
        for (int ks = 0; ks < 8; ks++) {
            const int ko = ks * 32 + quad * 8;
            bf16x8 a = *(const bf16x8*)&hs[0][ncol][ko];
            #pragma unroll
            for (int s = 0; s < 2; s++) {
                const int j = s ? j1 : j0;
                bf16x8 br = pack8(Wih1_f + (size_t)(j)       * 256 + ko);
                bf16x8 bz = pack8(Wih1_f + (size_t)(256 + j) * 256 + ko);
                bf16x8 bn = pack8(Wih1_f + (size_t)(512 + j) * 256 + ko);
                acc_r[s]  = MFMA(a, br, acc_r[s]);
                acc_z[s]  = MFMA(a, bz, acc_z[s]);
                acc_in[s] = MFMA(a, bn, acc_in[s]);
            }
        }
        #pragma unroll
        for (int s = 0; s < 2; s++) {
            const int j = s ? j1 : j0;
            #pragma unroll
            for (int r = 0; r < 4; r++) {
                float rg = sigm(acc_r[s][r] + b1R[j]);
                float zg = sigm(acc_z[s][r] + b1Z[j]);
                float nn = tanh_fast(acc_in[s][r] + b1IN[j] + rg * b1HN[j]);
                float hv = (1.f - zg) * nn;           // + zg*0
                hs[1][quad * 4 + r][j] = f2bf(hv);
            }
        }
        __syncthreads();   // h1 in hs[1]
    }

    // ---- heads ----
    {
        f32x4 acc_mu[2] = {{0,0,0,0},{0,0,0,0}};
        f32x4 acc_lv[2] = {{0,0,0,0},{0,0,0,0}};
        f32x4 acc_md[2] = {{0,0,0,0},{0,0,0,0}};
        const bool do_mean = (wave < 2), do_disp = (wave >= 2 && wave < 4);
        const int jm0 = (wave & 1) * 32 + ncol, jm1 = jm0 + 16;

        #pragma unroll 2
        for (int ks = 0; ks < 8; ks++) {
            const int ko = ks * 32 + quad * 8;
            bf16x8 a = *(const bf16x8*)&hs[1][ncol][ko];
            #pragma unroll
            for (int s = 0; s < 2; s++) {
                const int j = s ? j1 : j0;
                bf16x8 bmu8 = pack8(Wmu_f  + (size_t)j * 256 + ko);
                bf16x8 blv8 = pack8(Wstd_f + (size_t)j * 256 + ko);
                acc_mu[s] = MFMA(a, bmu8, acc_mu[s]);
                acc_lv[s] = MFMA(a, blv8, acc_lv[s]);
                if (do_mean || do_disp) {
                    const int jm = s ? jm1 : jm0;
                    bf16x8 md8 = do_mean ? pack8(Wmean_f + (size_t)jm * 256 + ko)
                                         : pack8(Wdisp_f + (size_t)jm * 256 + ko);
                    acc_md[s] = MFMA(a, md8, acc_md[s]);
                }
            }
        }
        #pragma unroll
        for (int s = 0; s < 2; s++) {
            const int j = s ? j1 : j0;
            const float bmu_v = bmu[j], blv_v = bstd[j];
            #pragma unroll
            for (int r = 0; r < 4; r++) {
                int b = b0 + quad * 4 + r;
                out[OFF_MU + b * 256 + j] = acc_mu[s][r] + bmu_v;
                out[OFF_LV + b * 256 + j] = acc_lv[s][r] + blv_v;
            }
        }
        if (do_mean) {
            #pragma unroll
            for (int s = 0; s < 2; s++) {
                const int jm = s ? jm1 : jm0;
                const float bm = bmean[jm];
                #pragma unroll
                for (int r = 0; r < 4; r++) {
                    int b = b0 + quad * 4 + r;
                    out[OFF_MEAN + b * 64 + jm] =
                        fminf(fmaxf(__expf(acc_md[s][r] + bm), 1e-5f), 1e6f);
                }
            }
        } else if (do_disp) {
            #pragma unroll
            for (int s = 0; s < 2; s++) {
                const int jm = s ? jm1 : jm0;
                const float bd = bdisp[jm];
                #pragma unroll
                for (int r = 0; r < 4; r++) {
                    int b = b0 + quad * 4 + r;
                    float v = acc_md[s][r] + bd;
                    float sp = (v > 20.f) ? v : log1pf(__expf(v));
                    out[OFF_DISP + b * 64 + jm] = fminf(fmaxf(sp, 1e-4f), 1e4f);
                }
            }
        }
    }
}

// ---------------------------------------------------------------------------
// Nets: R11-exact structure. grid (p=64, btile=4 of 16 rows) = 256 blocks,
// 512 thr = 8 waves, launch_bounds(512,2) -> 256 regs/wave budget.
// Wave owns 2 j-slices; all 3 gates' W_hh fragments register/AGPR-resident
// (192 regs). Preload via pack8 from fp32 (cvt kernel dropped).
// rcpf gates, ping-pong LDS, single barrier/step.
// ---------------------------------------------------------------------------
__global__ __launch_bounds__(512, 2) void nets_kernel(
    const float* __restrict__ X,
    const int*   __restrict__ conn,
    const float* __restrict__ Wih,
    const float* __restrict__ Whh_f,
    const float* __restrict__ bih,
    const float* __restrict__ bhh,
    const float* __restrict__ Wlin,
    const float* __restrict__ blin,
    const float* __restrict__ znoise,
    float*       __restrict__ out)
{
    const int p    = blockIdx.x;
    const int b0   = blockIdx.y * 16;
    const int tid  = threadIdx.x;
    const int wave = tid >> 6;
    const int lane = tid & 63;
    const int quad = lane >> 4;
    const int ncol = lane & 15;
    const int j0   = wave * 32 + ncol;
    const int j1   = j0 + 16;

    __shared__ __align__(16) unsigned short hs[2][16][264];
    __shared__ __align__(16) unsigned short xs[2][16][16];
    __shared__ __align__(16) unsigned short wih_s[768][16];
    __shared__ float bR[256], bZ[256], bIN[256], bHN[256], wlin_s[256];
    __shared__ float predw[2][8][16];
    __shared__ int   conn_s[16];

    for (int i = tid; i < 768 * 16; i += 512)
        (&wih_s[0][0])[i] = f2bf_fast(Wih[p * 768 * 16 + i]);
    for (int i = tid; i < 256; i += 512) {
        bR[i]  = bih[p * 768 + i]       + bhh[p * 768 + i];
        bZ[i]  = bih[p * 768 + 256 + i] + bhh[p * 768 + 256 + i];
        bIN[i] = bih[p * 768 + 512 + i];
        bHN[i] = bhh[p * 768 + 512 + i];
        wlin_s[i] = Wlin[p * 256 + i];
    }
    if (tid < 16) conn_s[tid] = conn[p * 16 + tid];

    for (int i = tid; i < 16 * 264; i += 512) {
        int bb = i / 264, jj = i - bb * 264;
        unsigned short v = 0;
        if (jj < 256) {
            int gi = (b0 + bb) * 256 + jj;
            v = f2bf(out[OFF_MU + gi] + __expf(0.5f * out[OFF_LV + gi]) * znoise[gi]);
        }
        hs[0][bb][jj] = v;
    }
    if (tid < 256) xs[0][tid >> 4][tid & 15] = 0;

    float hreg[2][4];
    #pragma unroll
    for (int s = 0; s < 2; s++)
        #pragma unroll
        for (int r = 0; r < 4; r++) {
            int gi = (b0 + quad * 4 + r) * 256 + (s ? j1 : j0);
            hreg[s][r] = out[OFF_MU + gi] + __expf(0.5f * out[OFF_LV + gi]) * znoise[gi];
        }

    // preload W_hh fragments (loop-invariant, via pack8 from fp32)
    const size_t whh_off = (size_t)p * 768 * 256;
    bf16x8 w_r[2][8], w_z[2][8], w_n[2][8];
    #pragma unroll
    for (int s = 0; s < 2; s++) {
        const int j = s ? j1 : j0;
        #pragma unroll
        for (int k0 = 0; k0 < 8; k0++) {
            const int ko = k0 * 32 + quad * 8;
            w_r[s][k0] = pack8(Whh_f + whh_off + (size_t)(j)       * 256 + ko);
            w_z[s][k0] = pack8(Whh_f + whh_off + (size_t)(256 + j) * 256 + ko);
            w_n[s][k0] = pack8(Whh_f + whh_off + (size_t)(512 + j) * 256 + ko);
        }
    }

    __syncthreads();

    const float blin_v = blin[p];
    const bf16x8 ZERO8 = {0, 0, 0, 0, 0, 0, 0, 0};

    for (int t = 0; t < 100; t++) {
        const int cur = t & 1, nxt = cur ^ 1;
        f32x4 acc_r[2]  = {{0,0,0,0},{0,0,0,0}};
        f32x4 acc_z[2]  = {{0,0,0,0},{0,0,0,0}};
        f32x4 acc_in[2] = {{0,0,0,0},{0,0,0,0}};
        f32x4 acc_hn[2] = {{0,0,0,0},{0,0,0,0}};

        // x part (K=16 zero-padded)
        {
            bf16x8 a, br0, bz0, bn0, br1, bz1, bn1;
            if (quad < 2) {
                a   = *(const bf16x8*)&xs[cur][ncol][quad * 8];
                br0 = *(const bf16x8*)&wih_s[j0][quad * 8];
                bz0 = *(const bf16x8*)&wih_s[256 + j0][quad * 8];
                bn0 = *(const bf16x8*)&wih_s[512 + j0][quad * 8];
                br1 = *(const bf16x8*)&wih_s[j1][quad * 8];
                bz1 = *(const bf16x8*)&wih_s[256 + j1][quad * 8];
                bn1 = *(const bf16x8*)&wih_s[512 + j1][quad * 8];
            } else {
                a = ZERO8; br0 = bz0 = bn0 = br1 = bz1 = bn1 = ZERO8;
            }
            acc_r[0]  = MFMA(a, br0, acc_r[0]);  acc_r[1]  = MFMA(a, br1, acc_r[1]);
            acc_z[0]  = MFMA(a, bz0, acc_z[0]);  acc_z[1]  = MFMA(a, bz1, acc_z[1]);
            acc_in[0] = MFMA(a, bn0, acc_in[0]); acc_in[1] = MFMA(a, bn1, acc_in[1]);
        }
        // h part: weights from registers
        #pragma unroll
        for (int k0 = 0; k0 < 8; k0++) {
            bf16x8 a = *(const bf16x8*)&hs[cur][ncol][k0 * 32 + quad * 8];
            acc_r[0]  = MFMA(a, w_r[0][k0], acc_r[0]);
            acc_r[1]  = MFMA(a, w_r[1][k0], acc_r[1]);
            acc_z[0]  = MFMA(a, w_z[0][k0], acc_z[0]);
            acc_z[1]  = MFMA(a, w_z[1][k0], acc_z[1]);
            acc_hn[0] = MFMA(a, w_n[0][k0], acc_hn[0]);
            acc_hn[1] = MFMA(a, w_n[1][k0], acc_hn[1]);
        }

        // gates + state update
        float pv[4] = {0.f, 0.f, 0.f, 0.f};
        #pragma unroll
        for (int s = 0; s < 2; s++) {
            const int j = s ? j1 : j0;
            const float b_r = bR[j], b_z = bZ[j], b_in = bIN[j], b_hn = bHN[j];
            const float wl = wlin_s[j];
            #pragma unroll
            for (int r = 0; r < 4; r++) {
                float rg = sigm(acc_r[s][r] + b_r);
                float zg = sigm(acc_z[s][r] + b_z);
                float nn = tanh_fast(acc_in[s][r] + b_in + rg * (acc_hn[s][r] + b_hn));
                float hv = (1.f - zg) * nn + zg * hreg[s][r];
                hreg[s][r] = hv;
                pv[r] += fmaxf(hv, 0.f) * wl;
            }
        }
        // reduce across 16 ncol lanes
        #pragma unroll
        for (int r = 0; r < 4; r++) {
            float v = pv[r];
            v += __shfl_xor(v, 1, 64);
            v += __shfl_xor(v, 2, 64);
            v += __shfl_xor(v, 4, 64);
            v += __shfl_xor(v, 8, 64);
            pv[r] = v;
        }

        // writes into nxt buffers (disjoint from cur)
        #pragma unroll
        for (int r = 0; r < 4; r++) {
            hs[nxt][quad * 4 + r][j0] = f2bf_fast(hreg[0][r]);
            hs[nxt][quad * 4 + r][j1] = f2bf_fast(hreg[1][r]);
        }
        if (ncol == 0) {
            #pragma unroll
            for (int r = 0; r < 4; r++)
                predw[cur][wave][quad * 4 + r] = pv[r];
        }
        if (tid < 256) {
            int gb = tid >> 4, gk = tid & 15;
            unsigned short v = 0;
            if (t < 99) v = f2bf_fast(X[(size_t)((b0 + gb) * 110 + (10 + t)) * 64 + conn_s[gk]]);
            xs[nxt][gb][gk] = v;
        }

        __syncthreads();   // orders: cur reads & nxt/predw[cur] writes

        if (tid < 16) {
            float s = blin_v;
            #pragma unroll
            for (int w = 0; w < 8; w++) s += predw[cur][w][tid];
            out[(size_t)(p * 64 + b0 + tid) * 100 + t] = s;
        }
    }
}

// ---------------------------------------------------------------------------
extern "C" void kernel_launch(void* const* d_in, const int* in_sizes, int n_in,
                              void* d_out, int out_size, void* d_ws, size_t ws_size,
                              hipStream_t stream) {
    const float* X      = (const float*)d_in[0];
    const int*   conn   = (const int*)d_in[1];
    const float* Wihl   = (const float*)d_in[2];
    const float* Whhl   = (const float*)d_in[3];
    const float* bihl   = (const float*)d_in[4];
    const float* bhhl   = (const float*)d_in[5];
    const float* Wih1   = (const float*)d_in[6];
    // d_in[7] = W_hh_1 unused: gru_1's h0 is 0, so gh reduces to b_hh_1
    const float* bih1   = (const float*)d_in[8];
    const float* bhh1   = (const float*)d_in[9];
    const float* Wmu    = (const float*)d_in[10];
    const float* bmu    = (const float*)d_in[11];
    const float* Wstd   = (const float*)d_in[12];
    const float* bstd   = (const float*)d_in[13];
    const float* Wmean  = (const float*)d_in[14];
    const float* bmean  = (const float*)d_in[15];
    const float* Wdisp  = (const float*)d_in[16];
    const float* bdisp  = (const float*)d_in[17];
    const float* Wihn   = (const float*)d_in[18];
    const float* Whhn   = (const float*)d_in[19];
    const float* bihn   = (const float*)d_in[20];
    const float* bhhn   = (const float*)d_in[21];
    const float* Wlin   = (const float*)d_in[22];
    const float* blin   = (const float*)d_in[23];
    const float* znoise = (const float*)d_in[24];

    float* out = (float*)d_out;
    (void)d_ws; (void)ws_size;   // cvt dropped: kernels pack8 from fp32

    encoder_mfma<<<4, 512, 0, stream>>>(
        X, Wihl, Whhl, bihl, bhhl, Wih1, bih1, bhh1,
        Wmu, bmu, Wstd, bstd, Wmean, bmean, Wdisp, bdisp, out);

    nets_kernel<<<dim3(64, 4), 512, 0, stream>>>(
        X, conn, Wihn, Whhn, bihn, bhhn, Wlin, blin, znoise, out);
}